// Round 1
// baseline (690.854 us; speedup 1.0000x reference)
//
#include <hip/hip_runtime.h>

#define B_   2
#define S_   2048
#define HID_ 2048
#define NH_  16
#define HD_  128

typedef float  f32x4  __attribute__((ext_vector_type(4)));
typedef __bf16 bf16x8 __attribute__((ext_vector_type(8)));

__device__ __forceinline__ unsigned short f2bf(float f) {
  union { float fv; unsigned u; } v; v.fv = f;
  unsigned r = v.u + 0x7FFFu + ((v.u >> 16) & 1u);  // RNE
  return (unsigned short)(r >> 16);
}
__device__ __forceinline__ float bf2f(unsigned short h) {
  union { unsigned u; float fv; } v; v.u = ((unsigned)h) << 16;
  return v.fv;
}

// async global->LDS, 16B per lane; lds must be wave-uniform base (lane*16 added by HW)
__device__ __forceinline__ void gload16(const void* g, void* lds) {
  __builtin_amdgcn_global_load_lds(
      (const __attribute__((address_space(1))) void*)g,
      (__attribute__((address_space(3))) void*)lds, 16, 0, 0);
}

// ---------------- cast fp32 -> bf16 ----------------
__global__ void cast_f32_bf16(const float* __restrict__ src,
                              unsigned short* __restrict__ dst, int n4) {
  int i = blockIdx.x * blockDim.x + threadIdx.x;
  int stride = gridDim.x * blockDim.x;
  for (; i < n4; i += stride) {
    float4 v = ((const float4*)src)[i];
    ushort4 o;
    o.x = f2bf(v.x); o.y = f2bf(v.y); o.z = f2bf(v.z); o.w = f2bf(v.w);
    ((ushort4*)dst)[i] = o;
  }
}

// ---------------- GEMM: C[M,N] = A[M,K] * B[N,K]^T (bf16 in, fp32 acc) ----------------
// EPI 0: fp32 row-major; EPI 1: bf16 row-major; EPI 2: bf16 scattered to (B,NH,S,HD)
template <int EPI>
__global__ __launch_bounds__(256, 2)
void gemm_bt(const unsigned short* __restrict__ A,
             const unsigned short* __restrict__ Bw,
             void* __restrict__ Cout, int M, int N, int K) {
  __shared__ __align__(16) unsigned short As[128 * 32];
  __shared__ __align__(16) unsigned short Bs[128 * 32];
  const int tid = threadIdx.x, lane = tid & 63, w = tid >> 6;
  const int n0 = blockIdx.x * 128, m0 = blockIdx.y * 128;
  const int wm = (w & 1) * 64, wn = (w >> 1) * 64;
  const int rowq = lane & 15;
  const int koff = (lane >> 4) * 8;
  const int lr0 = (lane >> 4) * 4;

  f32x4 acc[4][4];
  for (int i = 0; i < 4; ++i)
    for (int j = 0; j < 4; ++j)
      for (int r = 0; r < 4; ++r) acc[i][j][r] = 0.f;

  for (int k0 = 0; k0 < K; k0 += 32) {
    __syncthreads();
    // stage A,B tiles: 512 chunks of 16B each
    for (int c = 0; c < 2; ++c) {
      int chunk = (w * 2 + c) * 64 + lane;
      int row = chunk >> 2, cc = chunk & 3;
      gload16(A + (size_t)(m0 + row) * K + k0 + cc * 8, As + (w * 2 + c) * 512);
      gload16(Bw + (size_t)(n0 + row) * K + k0 + cc * 8, Bs + (w * 2 + c) * 512);
    }
    __syncthreads();
    bf16x8 af[4], bfv[4];
    for (int i = 0; i < 4; ++i) {
      af[i]  = *(const bf16x8*)&As[(wm + i * 16 + rowq) * 32 + koff];
      bfv[i] = *(const bf16x8*)&Bs[(wn + i * 16 + rowq) * 32 + koff];
    }
    for (int mi = 0; mi < 4; ++mi)
      for (int ni = 0; ni < 4; ++ni)
        acc[mi][ni] = __builtin_amdgcn_mfma_f32_16x16x32_bf16(af[mi], bfv[ni], acc[mi][ni], 0, 0, 0);
  }

  for (int mi = 0; mi < 4; ++mi)
    for (int ni = 0; ni < 4; ++ni)
      for (int r = 0; r < 4; ++r) {
        int r_ = m0 + wm + mi * 16 + lr0 + r;
        int c_ = n0 + wn + ni * 16 + rowq;
        float v = acc[mi][ni][r];
        if (EPI == 0) {
          ((float*)Cout)[(size_t)r_ * N + c_] = v;
        } else if (EPI == 1) {
          ((unsigned short*)Cout)[(size_t)r_ * N + c_] = f2bf(v);
        } else {
          int b = r_ >> 11, s = r_ & 2047, h = c_ >> 7, d = c_ & 127;
          ((unsigned short*)Cout)[(((size_t)(b * NH_ + h) * S_ + s) * HD_) + d] = f2bf(v);
        }
      }
}

// ---------------- RoPE in-place on Q,K in (B,NH,S,HD) bf16 ----------------
__global__ void rope_kernel(unsigned short* __restrict__ Qb,
                            unsigned short* __restrict__ Kb,
                            const int* __restrict__ pos_ids) {
  const int bhs = blockIdx.x;       // (b*NH+h)*S + s
  const int d = threadIdx.x;        // 0..63 (pair d, d+64)
  const int s = bhs & (S_ - 1);
  const int b = bhs >> 15;          // NH_*S_ = 32768
  const int p = pos_ids[b * S_ + s];
  const float f = expf(-(float)d * (9.210340371976184f / 64.f));  // 10000^(-d/64)
  float sn, cs;
  sincosf((float)p * f, &sn, &cs);
  size_t base = (size_t)bhs * HD_;
  {
    float x1 = bf2f(Qb[base + d]), x2 = bf2f(Qb[base + d + 64]);
    Qb[base + d]      = f2bf(x1 * cs - x2 * sn);
    Qb[base + d + 64] = f2bf(x2 * cs + x1 * sn);
  }
  {
    float x1 = bf2f(Kb[base + d]), x2 = bf2f(Kb[base + d + 64]);
    Kb[base + d]      = f2bf(x1 * cs - x2 * sn);
    Kb[base + d + 64] = f2bf(x2 * cs + x1 * sn);
  }
}

// ---------------- transpose V: (B,S,HID) bf16 -> (B,NH,HD,S) bf16 ----------------
__global__ __launch_bounds__(256)
void transpose_v(const unsigned short* __restrict__ Vin,
                 unsigned short* __restrict__ Vt) {
  __shared__ unsigned short t[64 * 66];
  const int s0 = blockIdx.x * 64, d0 = blockIdx.y * 64, bh = blockIdx.z;
  const int b = bh >> 4, h = bh & 15;
  for (int it = 0; it < 16; ++it) {
    int lin = it * 256 + threadIdx.x;
    int sl = lin >> 6, dl = lin & 63;
    t[sl * 66 + dl] = Vin[(size_t)(b * S_ + s0 + sl) * HID_ + h * HD_ + d0 + dl];
  }
  __syncthreads();
  for (int it = 0; it < 16; ++it) {
    int lin = it * 256 + threadIdx.x;
    int dl = lin >> 6, sl = lin & 63;
    Vt[((size_t)bh * HD_ + d0 + dl) * S_ + s0 + sl] = t[sl * 66 + dl];
  }
}

// ---------------- fused causal flash attention ----------------
// Q,K: (B,NH,S,HD) bf16 (post-RoPE); Vt: (B,NH,HD,S) bf16; Ob: (B,S,HID) bf16
__global__ __launch_bounds__(256, 2)
void attn_fused(const unsigned short* __restrict__ Qb,
                const unsigned short* __restrict__ Kb,
                const unsigned short* __restrict__ Vt,
                unsigned short* __restrict__ Ob) {
  __shared__ __align__(16) unsigned short Qs[64 * 128];
  __shared__ __align__(16) unsigned short Ks[64 * 128];
  __shared__ __align__(16) unsigned short Vts[128 * 64];
  __shared__ __align__(16) unsigned short Ps[4 * 16 * 64];

  const int tid = threadIdx.x, lane = tid & 63, w = tid >> 6;
  const int qt = blockIdx.x, bh = blockIdx.y;
  const int q0 = qt * 64;
  const int b = bh >> 4, h = bh & 15;
  const int rowq = lane & 15;
  const int koff = (lane >> 4) * 8;
  const int lr0 = (lane >> 4) * 4;
  const size_t qkbase = (size_t)bh * (S_ * HD_);

  // stage Q tile (64x128): 1024 chunks
  for (int c = 0; c < 4; ++c) {
    int chunk = (w * 4 + c) * 64 + lane;
    int row = chunk >> 4, cc = chunk & 15;
    gload16(Qb + qkbase + (size_t)(q0 + row) * HD_ + cc * 8, Qs + (w * 4 + c) * 512);
  }

  f32x4 oacc[8];
  for (int i = 0; i < 8; ++i)
    for (int r = 0; r < 4; ++r) oacc[i][r] = 0.f;
  float m_r[4] = {-3e38f, -3e38f, -3e38f, -3e38f};
  float l_r[4] = {0.f, 0.f, 0.f, 0.f};

  const int nkt = qt + 1;  // causal: only tiles with keys <= q0+63
  for (int kt = 0; kt < nkt; ++kt) {
    __syncthreads();  // previous iteration's readers done (also fences Q stage on kt=0)
    for (int c = 0; c < 4; ++c) {
      int chunk = (w * 4 + c) * 64 + lane;
      int row = chunk >> 4, cc = chunk & 15;
      gload16(Kb + qkbase + (size_t)(kt * 64 + row) * HD_ + cc * 8, Ks + (w * 4 + c) * 512);
      int d = chunk >> 3, c2 = chunk & 7;
      gload16(Vt + ((size_t)bh * HD_ + d) * S_ + kt * 64 + c2 * 8, Vts + (w * 4 + c) * 512);
    }
    __syncthreads();

    // S = Q K^T : wave handles rows [w*16, w*16+16), all 64 cols
    f32x4 sacc[4];
    for (int n = 0; n < 4; ++n)
      for (int r = 0; r < 4; ++r) sacc[n][r] = 0.f;
    const int arow = w * 16 + rowq;
    for (int t = 0; t < 4; ++t) {
      bf16x8 af = *(const bf16x8*)&Qs[arow * 128 + t * 32 + koff];
      for (int n = 0; n < 4; ++n) {
        bf16x8 bk = *(const bf16x8*)&Ks[(n * 16 + rowq) * 128 + t * 32 + koff];
        sacc[n] = __builtin_amdgcn_mfma_f32_16x16x32_bf16(af, bk, sacc[n], 0, 0, 0);
      }
    }

    // scale + causal mask + online softmax (C layout: col=lane&15, row=lr0+r)
    const float scale = 0.08838834764831845f;  // 1/sqrt(128)
    float sv[4][4], tmax[4] = {-3e38f, -3e38f, -3e38f, -3e38f};
    for (int n = 0; n < 4; ++n) {
      int col = kt * 64 + n * 16 + rowq;
      for (int r = 0; r < 4; ++r) {
        int row = q0 + w * 16 + lr0 + r;
        float x = sacc[n][r] * scale;
        x = (col <= row) ? x : -1e30f;
        sv[n][r] = x;
        tmax[r] = fmaxf(tmax[r], x);
      }
    }
    for (int off = 1; off < 16; off <<= 1)
      for (int r = 0; r < 4; ++r) tmax[r] = fmaxf(tmax[r], __shfl_xor(tmax[r], off));
    float alpha[4];
    for (int r = 0; r < 4; ++r) {
      float mn = fmaxf(m_r[r], tmax[r]);
      alpha[r] = __expf(m_r[r] - mn);
      m_r[r] = mn;
    }
    float rs[4] = {0.f, 0.f, 0.f, 0.f};
    for (int n = 0; n < 4; ++n)
      for (int r = 0; r < 4; ++r) {
        float p = __expf(sv[n][r] - m_r[r]);
        sv[n][r] = p;
        rs[r] += p;
      }
    for (int off = 1; off < 16; off <<= 1)
      for (int r = 0; r < 4; ++r) rs[r] += __shfl_xor(rs[r], off);
    for (int r = 0; r < 4; ++r) l_r[r] = l_r[r] * alpha[r] + rs[r];
    for (int nd = 0; nd < 8; ++nd)
      for (int r = 0; r < 4; ++r) oacc[nd][r] *= alpha[r];

    // P: C-layout -> LDS -> A-layout (wave-private region, no barrier needed)
    unsigned short* pw = &Ps[w * 1024];
    for (int n = 0; n < 4; ++n)
      for (int r = 0; r < 4; ++r)
        pw[(lr0 + r) * 64 + n * 16 + rowq] = f2bf(sv[n][r]);

    // O += P V : rows = wave's 16 q-rows, cols = 128 d, K = 64 keys
    for (int t2 = 0; t2 < 2; ++t2) {
      bf16x8 pa = *(const bf16x8*)&pw[rowq * 64 + t2 * 32 + koff];
      for (int nd = 0; nd < 8; ++nd) {
        bf16x8 vb = *(const bf16x8*)&Vts[(nd * 16 + rowq) * 64 + t2 * 32 + koff];
        oacc[nd] = __builtin_amdgcn_mfma_f32_16x16x32_bf16(pa, vb, oacc[nd], 0, 0, 0);
      }
    }
  }

  // epilogue: divide by l, store bf16 to (B,S,HID)
  for (int nd = 0; nd < 8; ++nd) {
    int col = h * HD_ + nd * 16 + rowq;
    for (int r = 0; r < 4; ++r) {
      int row = q0 + w * 16 + lr0 + r;
      float o = oacc[nd][r] / l_r[r];
      Ob[(size_t)(b * S_ + row) * HID_ + col] = f2bf(o);
    }
  }
}

// ---------------- launcher ----------------
extern "C" void kernel_launch(void* const* d_in, const int* in_sizes, int n_in,
                              void* d_out, int out_size, void* d_ws, size_t ws_size,
                              hipStream_t stream) {
  (void)in_sizes; (void)n_in; (void)out_size; (void)ws_size;
  const float* hidden = (const float*)d_in[0];
  // d_in[1] = attention_mask (causal; reproduced analytically)
  const int* pos = (const int*)d_in[2];
  const float* Wq = (const float*)d_in[3];
  const float* Wk = (const float*)d_in[4];
  const float* Wv = (const float*)d_in[5];
  const float* Wo = (const float*)d_in[6];
  float* out = (float*)d_out;

  char* ws = (char*)d_ws;
  unsigned short* Xb   = (unsigned short*)(ws);               // 16 MB  (B,S,HID) bf16
  unsigned short* Wqb  = (unsigned short*)(ws + 16777216);    // 8 MB
  unsigned short* Wkb  = (unsigned short*)(ws + 25165824);    // 8 MB
  unsigned short* Wvb  = (unsigned short*)(ws + 33554432);    // 8 MB
  unsigned short* Wob  = (unsigned short*)(ws + 41943040);    // 8 MB
  unsigned short* Qb   = (unsigned short*)(ws + 50331648);    // 16 MB (B,NH,S,HD)
  unsigned short* Kb   = (unsigned short*)(ws + 67108864);    // 16 MB
  unsigned short* Vtmp = (unsigned short*)(ws + 83886080);    // 16 MB (B,S,HID)
  unsigned short* Vtb  = (unsigned short*)(ws + 100663296);   // 16 MB (B,NH,HD,S)
  unsigned short* Ob   = Xb;  // reuse: Xb dead after V GEMM   total ws: 112 MB

  cast_f32_bf16<<<1024, 256, 0, stream>>>(hidden, Xb, (B_ * S_ * HID_) / 4);
  cast_f32_bf16<<<512, 256, 0, stream>>>(Wq, Wqb, (HID_ * HID_) / 4);
  cast_f32_bf16<<<512, 256, 0, stream>>>(Wk, Wkb, (HID_ * HID_) / 4);
  cast_f32_bf16<<<512, 256, 0, stream>>>(Wv, Wvb, (HID_ * HID_) / 4);
  cast_f32_bf16<<<512, 256, 0, stream>>>(Wo, Wob, (HID_ * HID_) / 4);

  dim3 gg(HID_ / 128, (B_ * S_) / 128);  // (16, 32)
  gemm_bt<2><<<gg, 256, 0, stream>>>(Xb, Wqb, Qb, B_ * S_, HID_, HID_);
  gemm_bt<2><<<gg, 256, 0, stream>>>(Xb, Wkb, Kb, B_ * S_, HID_, HID_);
  gemm_bt<1><<<gg, 256, 0, stream>>>(Xb, Wvb, Vtmp, B_ * S_, HID_, HID_);

  rope_kernel<<<B_ * NH_ * S_, 64, 0, stream>>>(Qb, Kb, pos);

  dim3 tg(S_ / 64, HD_ / 64, B_ * NH_);  // (32, 2, 32)
  transpose_v<<<tg, 256, 0, stream>>>(Vtmp, Vtb);

  dim3 ag(S_ / 64, B_ * NH_);  // (32, 32)
  attn_fused<<<ag, 256, 0, stream>>>(Qb, Kb, Vtb, Ob);

  gemm_bt<0><<<gg, 256, 0, stream>>>(Ob, Wob, out, B_ * S_, HID_, HID_);
}

// Round 2
// 544.896 us; speedup vs baseline: 1.2679x; 1.2679x over previous
//
#include <hip/hip_runtime.h>

#define B_   2
#define S_   2048
#define HID_ 2048
#define NH_  16
#define HD_  128

typedef float  f32x4  __attribute__((ext_vector_type(4)));
typedef __bf16 bf16x8 __attribute__((ext_vector_type(8)));

__device__ __forceinline__ unsigned short f2bf(float f) {
  union { float fv; unsigned u; } v; v.fv = f;
  unsigned r = v.u + 0x7FFFu + ((v.u >> 16) & 1u);  // RNE
  return (unsigned short)(r >> 16);
}
__device__ __forceinline__ float bf2f(unsigned short h) {
  union { unsigned u; float fv; } v; v.u = ((unsigned)h) << 16;
  return v.fv;
}

// async global->LDS, 16B per lane (GEMM staging only; LDS dst must be contiguous)
__device__ __forceinline__ void gload16(const void* g, void* lds) {
  __builtin_amdgcn_global_load_lds(
      (const __attribute__((address_space(1))) void*)g,
      (__attribute__((address_space(3))) void*)lds, 16, 0, 0);
}

// ---------------- fused cast fp32 -> bf16 for hidden + 4 weights ----------------
#define H4_ (B_ * S_ * HID_ / 4)
#define W4_ (HID_ * HID_ / 4)
__global__ void cast_all(const float* __restrict__ h,  const float* __restrict__ wq,
                         const float* __restrict__ wk, const float* __restrict__ wv,
                         const float* __restrict__ wo,
                         unsigned short* __restrict__ xb,  unsigned short* __restrict__ wqb,
                         unsigned short* __restrict__ wkb, unsigned short* __restrict__ wvb,
                         unsigned short* __restrict__ wob) {
  const int total = H4_ + 4 * W4_;
  int i = blockIdx.x * blockDim.x + threadIdx.x;
  int stride = gridDim.x * blockDim.x;
  for (; i < total; i += stride) {
    const float* src; unsigned short* dst; int j;
    if (i < H4_) { src = h; dst = xb; j = i; }
    else {
      int k = i - H4_, wsel = k >> 20;  // W4_ = 2^20
      j = k & (W4_ - 1);
      src = (wsel == 0) ? wq : (wsel == 1) ? wk : (wsel == 2) ? wv : wo;
      dst = (wsel == 0) ? wqb : (wsel == 1) ? wkb : (wsel == 2) ? wvb : wob;
    }
    float4 v = ((const float4*)src)[j];
    ushort4 o;
    o.x = f2bf(v.x); o.y = f2bf(v.y); o.z = f2bf(v.z); o.w = f2bf(v.w);
    ((ushort4*)dst)[j] = o;
  }
}

// ---------------- GEMM: C[M,N] = A[M,K] * B[N,K]^T (bf16 in, fp32 acc) ----------------
// EPI 0: fp32 row-major; EPI 1: bf16 row-major; EPI 2: bf16 scattered to (B,NH,S,HD)
template <int EPI>
__global__ __launch_bounds__(256, 2)
void gemm_bt(const unsigned short* __restrict__ A,
             const unsigned short* __restrict__ Bw,
             void* __restrict__ Cout, int M, int N, int K) {
  __shared__ __align__(16) unsigned short As[128 * 32];
  __shared__ __align__(16) unsigned short Bs[128 * 32];
  const int tid = threadIdx.x, lane = tid & 63, w = tid >> 6;
  const int n0 = blockIdx.x * 128, m0 = blockIdx.y * 128;
  const int wm = (w & 1) * 64, wn = (w >> 1) * 64;
  const int rowq = lane & 15;
  const int koff = (lane >> 4) * 8;
  const int lr0 = (lane >> 4) * 4;

  f32x4 acc[4][4];
  for (int i = 0; i < 4; ++i)
    for (int j = 0; j < 4; ++j)
      for (int r = 0; r < 4; ++r) acc[i][j][r] = 0.f;

  for (int k0 = 0; k0 < K; k0 += 32) {
    __syncthreads();
    for (int c = 0; c < 2; ++c) {
      int chunk = (w * 2 + c) * 64 + lane;
      int row = chunk >> 2, cc = chunk & 3;
      gload16(A + (size_t)(m0 + row) * K + k0 + cc * 8, As + (w * 2 + c) * 512);
      gload16(Bw + (size_t)(n0 + row) * K + k0 + cc * 8, Bs + (w * 2 + c) * 512);
    }
    __syncthreads();
    bf16x8 af[4], bfv[4];
    for (int i = 0; i < 4; ++i) {
      af[i]  = *(const bf16x8*)&As[(wm + i * 16 + rowq) * 32 + koff];
      bfv[i] = *(const bf16x8*)&Bs[(wn + i * 16 + rowq) * 32 + koff];
    }
    for (int mi = 0; mi < 4; ++mi)
      for (int ni = 0; ni < 4; ++ni)
        acc[mi][ni] = __builtin_amdgcn_mfma_f32_16x16x32_bf16(af[mi], bfv[ni], acc[mi][ni], 0, 0, 0);
  }

  for (int mi = 0; mi < 4; ++mi)
    for (int ni = 0; ni < 4; ++ni)
      for (int r = 0; r < 4; ++r) {
        int r_ = m0 + wm + mi * 16 + lr0 + r;
        int c_ = n0 + wn + ni * 16 + rowq;
        float v = acc[mi][ni][r];
        if (EPI == 0) {
          ((float*)Cout)[(size_t)r_ * N + c_] = v;
        } else if (EPI == 1) {
          ((unsigned short*)Cout)[(size_t)r_ * N + c_] = f2bf(v);
        } else {
          int b = r_ >> 11, s = r_ & 2047, h = c_ >> 7, d = c_ & 127;
          ((unsigned short*)Cout)[(((size_t)(b * NH_ + h) * S_ + s) * HD_) + d] = f2bf(v);
        }
      }
}

// ---------------- RoPE in-place on Q,K in (B,NH,S,HD) bf16 ----------------
__global__ void rope_kernel(unsigned short* __restrict__ Qb,
                            unsigned short* __restrict__ Kb,
                            const int* __restrict__ pos_ids) {
  const int bhs = blockIdx.x;       // (b*NH+h)*S + s
  const int d = threadIdx.x;        // 0..63 (pair d, d+64)
  const int s = bhs & (S_ - 1);
  const int b = bhs >> 15;          // NH_*S_ = 32768
  const int p = pos_ids[b * S_ + s];
  const float f = expf(-(float)d * (9.210340371976184f / 64.f));  // 10000^(-d/64)
  float sn, cs;
  sincosf((float)p * f, &sn, &cs);
  size_t base = (size_t)bhs * HD_;
  {
    float x1 = bf2f(Qb[base + d]), x2 = bf2f(Qb[base + d + 64]);
    Qb[base + d]      = f2bf(x1 * cs - x2 * sn);
    Qb[base + d + 64] = f2bf(x2 * cs + x1 * sn);
  }
  {
    float x1 = bf2f(Kb[base + d]), x2 = bf2f(Kb[base + d + 64]);
    Kb[base + d]      = f2bf(x1 * cs - x2 * sn);
    Kb[base + d + 64] = f2bf(x2 * cs + x1 * sn);
  }
}

// ---------------- transpose V: (B,S,HID) bf16 -> (B,NH,HD,S) bf16 ----------------
__global__ __launch_bounds__(256)
void transpose_v(const unsigned short* __restrict__ Vin,
                 unsigned short* __restrict__ Vt) {
  __shared__ unsigned short t[64 * 66];
  const int s0 = blockIdx.x * 64, d0 = blockIdx.y * 64, bh = blockIdx.z;
  const int b = bh >> 4, h = bh & 15;
  for (int it = 0; it < 16; ++it) {
    int lin = it * 256 + threadIdx.x;
    int sl = lin >> 6, dl = lin & 63;
    t[sl * 66 + dl] = Vin[(size_t)(b * S_ + s0 + sl) * HID_ + h * HD_ + d0 + dl];
  }
  __syncthreads();
  for (int it = 0; it < 16; ++it) {
    int lin = it * 256 + threadIdx.x;
    int dl = lin >> 6, sl = lin & 63;
    Vt[((size_t)bh * HD_ + d0 + dl) * S_ + s0 + sl] = t[sl * 66 + dl];
  }
}

// ---------------- fused causal flash attention (v2) ----------------
// Padded LDS (stride % 128B == 16B -> 2-way bank aliasing only, free).
// K/V staged via VGPRs with register prefetch of tile kt+1 during compute of kt.
// Q fragments held in registers for the whole k-loop. 3 blocks/CU (44 KB LDS).
#define KS_LD 136   // 64x128 K tile, padded
#define VS_LD 72    // 128x64 V^T tile, padded
#define PS_LD 72    // 16x64 P tile per wave, padded
__global__ __launch_bounds__(256, 3)
void attn_fused(const unsigned short* __restrict__ Qb,
                const unsigned short* __restrict__ Kb,
                const unsigned short* __restrict__ Vt,
                unsigned short* __restrict__ Ob) {
  __shared__ __align__(16) unsigned short Ks[64 * KS_LD];
  __shared__ __align__(16) unsigned short Vts[128 * VS_LD];
  __shared__ __align__(16) unsigned short Ps[4 * 16 * PS_LD];

  const int tid = threadIdx.x, lane = tid & 63, w = tid >> 6;
  const int bh = blockIdx.x;                  // fast dim: spreads heads across XCDs
  const int qt = (gridDim.y - 1) - blockIdx.y;  // descending: longest blocks first (LPT)
  const int q0 = qt * 64;
  const int b = bh >> 4, h = bh & 15;
  const int rowq = lane & 15;
  const int koff = (lane >> 4) * 8;
  const int lr0 = (lane >> 4) * 4;
  const size_t qkbase = (size_t)bh * (S_ * HD_);
  const size_t vbase  = (size_t)bh * (HD_ * S_);

  // Q fragments direct from global, held in regs across the whole k-loop
  bf16x8 qf[4];
  {
    const unsigned short* qrow = Qb + qkbase + (size_t)(q0 + w * 16 + rowq) * HD_;
    for (int t = 0; t < 4; ++t) qf[t] = *(const bf16x8*)(qrow + t * 32 + koff);
  }

  // staging decomposition (256 threads, 16B chunks, 4 passes each)
  const int krow = tid >> 4, kcol = (tid & 15) * 8;  // K: 16 rows/pass
  const int vrow = tid >> 3, vcol = (tid & 7) * 8;   // V^T: 32 rows/pass

  f32x4 oacc[8];
  for (int i = 0; i < 8; ++i)
    for (int r = 0; r < 4; ++r) oacc[i][r] = 0.f;
  float m_r[4] = {-3e38f, -3e38f, -3e38f, -3e38f};
  float l_r[4] = {0.f, 0.f, 0.f, 0.f};

  const int nkt = qt + 1;

  // prefetch tile 0 into regs
  float4 kreg[4], vreg[4];
  for (int p = 0; p < 4; ++p) {
    kreg[p] = *(const float4*)(Kb + qkbase + (size_t)(krow + p * 16) * HD_ + kcol);
    vreg[p] = *(const float4*)(Vt + vbase + (size_t)(vrow + p * 32) * S_ + vcol);
  }

  for (int kt = 0; kt < nkt; ++kt) {
    __syncthreads();  // previous tile's readers done
    for (int p = 0; p < 4; ++p)
      *(float4*)&Ks[(krow + p * 16) * KS_LD + kcol] = kreg[p];
    for (int p = 0; p < 4; ++p)
      *(float4*)&Vts[(vrow + p * 32) * VS_LD + vcol] = vreg[p];
    // prefetch next tile into regs; latency hides under this tile's compute
    if (kt + 1 < nkt) {
      for (int p = 0; p < 4; ++p) {
        kreg[p] = *(const float4*)(Kb + qkbase + (size_t)((kt + 1) * 64 + krow + p * 16) * HD_ + kcol);
        vreg[p] = *(const float4*)(Vt + vbase + (size_t)(vrow + p * 32) * S_ + (kt + 1) * 64 + vcol);
      }
    }
    __syncthreads();

    // S = Q K^T : wave handles q-rows [w*16, w*16+16), all 64 keys
    f32x4 sacc[4];
    for (int n = 0; n < 4; ++n)
      for (int r = 0; r < 4; ++r) sacc[n][r] = 0.f;
    for (int t = 0; t < 4; ++t)
      for (int n = 0; n < 4; ++n) {
        bf16x8 bk = *(const bf16x8*)&Ks[(n * 16 + rowq) * KS_LD + t * 32 + koff];
        sacc[n] = __builtin_amdgcn_mfma_f32_16x16x32_bf16(qf[t], bk, sacc[n], 0, 0, 0);
      }

    // scale (+ causal mask on diagonal tile only) + online softmax, in place
    const float scale = 0.08838834764831845f;  // 1/sqrt(128)
    float tmax[4] = {-3e38f, -3e38f, -3e38f, -3e38f};
    if (kt == qt) {
      for (int n = 0; n < 4; ++n) {
        int col = n * 16 + rowq;
        for (int r = 0; r < 4; ++r) {
          int row = w * 16 + lr0 + r;
          float x = sacc[n][r] * scale;
          x = (col <= row) ? x : -1e30f;
          sacc[n][r] = x;
          tmax[r] = fmaxf(tmax[r], x);
        }
      }
    } else {
      for (int n = 0; n < 4; ++n)
        for (int r = 0; r < 4; ++r) {
          float x = sacc[n][r] * scale;
          sacc[n][r] = x;
          tmax[r] = fmaxf(tmax[r], x);
        }
    }
    for (int off = 1; off < 16; off <<= 1)
      for (int r = 0; r < 4; ++r) tmax[r] = fmaxf(tmax[r], __shfl_xor(tmax[r], off));
    float alpha[4];
    for (int r = 0; r < 4; ++r) {
      float mn = fmaxf(m_r[r], tmax[r]);
      alpha[r] = __expf(m_r[r] - mn);
      m_r[r] = mn;
    }
    float rs[4] = {0.f, 0.f, 0.f, 0.f};
    for (int n = 0; n < 4; ++n)
      for (int r = 0; r < 4; ++r) {
        float p = __expf(sacc[n][r] - m_r[r]);
        sacc[n][r] = p;
        rs[r] += p;
      }
    for (int off = 1; off < 16; off <<= 1)
      for (int r = 0; r < 4; ++r) rs[r] += __shfl_xor(rs[r], off);
    for (int r = 0; r < 4; ++r) l_r[r] = l_r[r] * alpha[r] + rs[r];
    for (int nd = 0; nd < 8; ++nd)
      for (int r = 0; r < 4; ++r) oacc[nd][r] *= alpha[r];

    // P: C-layout -> LDS -> A-layout (wave-private region)
    unsigned short* pw = &Ps[w * 16 * PS_LD];
    for (int n = 0; n < 4; ++n)
      for (int r = 0; r < 4; ++r)
        pw[(lr0 + r) * PS_LD + n * 16 + rowq] = f2bf(sacc[n][r]);

    // O += P V
    for (int t2 = 0; t2 < 2; ++t2) {
      bf16x8 pa = *(const bf16x8*)&pw[rowq * PS_LD + t2 * 32 + koff];
      for (int nd = 0; nd < 8; ++nd) {
        bf16x8 vb = *(const bf16x8*)&Vts[(nd * 16 + rowq) * VS_LD + t2 * 32 + koff];
        oacc[nd] = __builtin_amdgcn_mfma_f32_16x16x32_bf16(pa, vb, oacc[nd], 0, 0, 0);
      }
    }
  }

  // epilogue: multiply by 1/l, store bf16 to (B,S,HID)
  float linv[4];
  for (int r = 0; r < 4; ++r) linv[r] = __builtin_amdgcn_rcpf(l_r[r]);
  for (int nd = 0; nd < 8; ++nd) {
    int col = h * HD_ + nd * 16 + rowq;
    for (int r = 0; r < 4; ++r) {
      int row = q0 + w * 16 + lr0 + r;
      Ob[(size_t)(b * S_ + row) * HID_ + col] = f2bf(oacc[nd][r] * linv[r]);
    }
  }
}

// ---------------- launcher ----------------
extern "C" void kernel_launch(void* const* d_in, const int* in_sizes, int n_in,
                              void* d_out, int out_size, void* d_ws, size_t ws_size,
                              hipStream_t stream) {
  (void)in_sizes; (void)n_in; (void)out_size; (void)ws_size;
  const float* hidden = (const float*)d_in[0];
  // d_in[1] = attention_mask (causal; reproduced analytically)
  const int* pos = (const int*)d_in[2];
  const float* Wq = (const float*)d_in[3];
  const float* Wk = (const float*)d_in[4];
  const float* Wv = (const float*)d_in[5];
  const float* Wo = (const float*)d_in[6];
  float* out = (float*)d_out;

  char* ws = (char*)d_ws;
  unsigned short* Xb   = (unsigned short*)(ws);               // 16 MB  (B,S,HID) bf16
  unsigned short* Wqb  = (unsigned short*)(ws + 16777216);    // 8 MB
  unsigned short* Wkb  = (unsigned short*)(ws + 25165824);    // 8 MB
  unsigned short* Wvb  = (unsigned short*)(ws + 33554432);    // 8 MB
  unsigned short* Wob  = (unsigned short*)(ws + 41943040);    // 8 MB
  unsigned short* Qb   = (unsigned short*)(ws + 50331648);    // 16 MB (B,NH,S,HD)
  unsigned short* Kb   = (unsigned short*)(ws + 67108864);    // 16 MB
  unsigned short* Vtmp = (unsigned short*)(ws + 83886080);    // 16 MB (B,S,HID)
  unsigned short* Vtb  = (unsigned short*)(ws + 100663296);   // 16 MB (B,NH,HD,S)
  unsigned short* Ob   = Xb;  // reuse: Xb dead after V GEMM   total ws: 112 MB

  cast_all<<<2048, 256, 0, stream>>>(hidden, Wq, Wk, Wv, Wo, Xb, Wqb, Wkb, Wvb, Wob);

  dim3 gg(HID_ / 128, (B_ * S_) / 128);  // (16, 32)
  gemm_bt<2><<<gg, 256, 0, stream>>>(Xb, Wqb, Qb, B_ * S_, HID_, HID_);
  gemm_bt<2><<<gg, 256, 0, stream>>>(Xb, Wkb, Kb, B_ * S_, HID_, HID_);
  gemm_bt<1><<<gg, 256, 0, stream>>>(Xb, Wvb, Vtmp, B_ * S_, HID_, HID_);

  rope_kernel<<<B_ * NH_ * S_, 64, 0, stream>>>(Qb, Kb, pos);

  dim3 tg(S_ / 64, HD_ / 64, B_ * NH_);  // (32, 2, 32)
  transpose_v<<<tg, 256, 0, stream>>>(Vtmp, Vtb);

  dim3 ag(B_ * NH_, S_ / 64);  // bh fast, qt slow (descending inside kernel)
  attn_fused<<<ag, 256, 0, stream>>>(Qb, Kb, Vtb, Ob);

  gemm_bt<0><<<gg, 256, 0, stream>>>(Ob, Wob, out, B_ * S_, HID_, HID_);
}

// Round 3
// 541.740 us; speedup vs baseline: 1.2753x; 1.0058x over previous
//
#include <hip/hip_runtime.h>

#define B_   2
#define S_   2048
#define HID_ 2048
#define NH_  16
#define HD_  128

typedef float  f32x4  __attribute__((ext_vector_type(4)));
typedef __bf16 bf16x8 __attribute__((ext_vector_type(8)));

__device__ __forceinline__ unsigned short f2bf(float f) {
  union { float fv; unsigned u; } v; v.fv = f;
  unsigned r = v.u + 0x7FFFu + ((v.u >> 16) & 1u);  // RNE
  return (unsigned short)(r >> 16);
}
__device__ __forceinline__ float bf2f(unsigned short h) {
  union { unsigned u; float fv; } v; v.u = ((unsigned)h) << 16;
  return v.fv;
}

// async global->LDS, 16B per lane (GEMM staging only; LDS dst must be contiguous)
__device__ __forceinline__ void gload16(const void* g, void* lds) {
  __builtin_amdgcn_global_load_lds(
      (const __attribute__((address_space(1))) void*)g,
      (__attribute__((address_space(3))) void*)lds, 16, 0, 0);
}

// ---------------- fused cast fp32 -> bf16 for hidden + 4 weights ----------------
#define H4_ (B_ * S_ * HID_ / 4)
#define W4_ (HID_ * HID_ / 4)
__global__ void cast_all(const float* __restrict__ h,  const float* __restrict__ wq,
                         const float* __restrict__ wk, const float* __restrict__ wv,
                         const float* __restrict__ wo,
                         unsigned short* __restrict__ xb,  unsigned short* __restrict__ wqb,
                         unsigned short* __restrict__ wkb, unsigned short* __restrict__ wvb,
                         unsigned short* __restrict__ wob) {
  const int total = H4_ + 4 * W4_;
  int i = blockIdx.x * blockDim.x + threadIdx.x;
  int stride = gridDim.x * blockDim.x;
  for (; i < total; i += stride) {
    const float* src; unsigned short* dst; int j;
    if (i < H4_) { src = h; dst = xb; j = i; }
    else {
      int k = i - H4_, wsel = k >> 20;  // W4_ = 2^20
      j = k & (W4_ - 1);
      src = (wsel == 0) ? wq : (wsel == 1) ? wk : (wsel == 2) ? wv : wo;
      dst = (wsel == 0) ? wqb : (wsel == 1) ? wkb : (wsel == 2) ? wvb : wob;
    }
    float4 v = ((const float4*)src)[j];
    ushort4 o;
    o.x = f2bf(v.x); o.y = f2bf(v.y); o.z = f2bf(v.z); o.w = f2bf(v.w);
    ((ushort4*)dst)[j] = o;
  }
}

// ---------------- GEMM: C[M,N] = A[M,K] * B[N,K]^T (bf16 in, fp32 acc) ----------------
// EPI 0: fp32 row-major; EPI 1: bf16 row-major; EPI 2: bf16 scattered to (B,NH,S,HD)
template <int EPI>
__global__ __launch_bounds__(256, 2)
void gemm_bt(const unsigned short* __restrict__ A,
             const unsigned short* __restrict__ Bw,
             void* __restrict__ Cout, int M, int N, int K) {
  __shared__ __align__(16) unsigned short As[128 * 32];
  __shared__ __align__(16) unsigned short Bs[128 * 32];
  const int tid = threadIdx.x, lane = tid & 63, w = tid >> 6;
  const int n0 = blockIdx.x * 128, m0 = blockIdx.y * 128;
  const int wm = (w & 1) * 64, wn = (w >> 1) * 64;
  const int rowq = lane & 15;
  const int koff = (lane >> 4) * 8;
  const int lr0 = (lane >> 4) * 4;

  f32x4 acc[4][4];
  for (int i = 0; i < 4; ++i)
    for (int j = 0; j < 4; ++j)
      for (int r = 0; r < 4; ++r) acc[i][j][r] = 0.f;

  for (int k0 = 0; k0 < K; k0 += 32) {
    __syncthreads();
    for (int c = 0; c < 2; ++c) {
      int chunk = (w * 2 + c) * 64 + lane;
      int row = chunk >> 2, cc = chunk & 3;
      gload16(A + (size_t)(m0 + row) * K + k0 + cc * 8, As + (w * 2 + c) * 512);
      gload16(Bw + (size_t)(n0 + row) * K + k0 + cc * 8, Bs + (w * 2 + c) * 512);
    }
    __syncthreads();
    bf16x8 af[4], bfv[4];
    for (int i = 0; i < 4; ++i) {
      af[i]  = *(const bf16x8*)&As[(wm + i * 16 + rowq) * 32 + koff];
      bfv[i] = *(const bf16x8*)&Bs[(wn + i * 16 + rowq) * 32 + koff];
    }
    for (int mi = 0; mi < 4; ++mi)
      for (int ni = 0; ni < 4; ++ni)
        acc[mi][ni] = __builtin_amdgcn_mfma_f32_16x16x32_bf16(af[mi], bfv[ni], acc[mi][ni], 0, 0, 0);
  }

  for (int mi = 0; mi < 4; ++mi)
    for (int ni = 0; ni < 4; ++ni)
      for (int r = 0; r < 4; ++r) {
        int r_ = m0 + wm + mi * 16 + lr0 + r;
        int c_ = n0 + wn + ni * 16 + rowq;
        float v = acc[mi][ni][r];
        if (EPI == 0) {
          ((float*)Cout)[(size_t)r_ * N + c_] = v;
        } else if (EPI == 1) {
          ((unsigned short*)Cout)[(size_t)r_ * N + c_] = f2bf(v);
        } else {
          int b = r_ >> 11, s = r_ & 2047, h = c_ >> 7, d = c_ & 127;
          ((unsigned short*)Cout)[(((size_t)(b * NH_ + h) * S_ + s) * HD_) + d] = f2bf(v);
        }
      }
}

// ---------------- RoPE in-place on Q,K in (B,NH,S,HD) bf16 ----------------
__global__ void rope_kernel(unsigned short* __restrict__ Qb,
                            unsigned short* __restrict__ Kb,
                            const int* __restrict__ pos_ids) {
  const int bhs = blockIdx.x;       // (b*NH+h)*S + s
  const int d = threadIdx.x;        // 0..63 (pair d, d+64)
  const int s = bhs & (S_ - 1);
  const int b = bhs >> 15;          // NH_*S_ = 32768
  const int p = pos_ids[b * S_ + s];
  const float f = expf(-(float)d * (9.210340371976184f / 64.f));  // 10000^(-d/64)
  float sn, cs;
  sincosf((float)p * f, &sn, &cs);
  size_t base = (size_t)bhs * HD_;
  {
    float x1 = bf2f(Qb[base + d]), x2 = bf2f(Qb[base + d + 64]);
    Qb[base + d]      = f2bf(x1 * cs - x2 * sn);
    Qb[base + d + 64] = f2bf(x2 * cs + x1 * sn);
  }
  {
    float x1 = bf2f(Kb[base + d]), x2 = bf2f(Kb[base + d + 64]);
    Kb[base + d]      = f2bf(x1 * cs - x2 * sn);
    Kb[base + d + 64] = f2bf(x2 * cs + x1 * sn);
  }
}

// ---------------- transpose V: (B,S,HID) bf16 -> (B,NH,HD,S) bf16 ----------------
__global__ __launch_bounds__(256)
void transpose_v(const unsigned short* __restrict__ Vin,
                 unsigned short* __restrict__ Vt) {
  __shared__ unsigned short t[64 * 66];
  const int s0 = blockIdx.x * 64, d0 = blockIdx.y * 64, bh = blockIdx.z;
  const int b = bh >> 4, h = bh & 15;
  for (int it = 0; it < 16; ++it) {
    int lin = it * 256 + threadIdx.x;
    int sl = lin >> 6, dl = lin & 63;
    t[sl * 66 + dl] = Vin[(size_t)(b * S_ + s0 + sl) * HID_ + h * HD_ + d0 + dl];
  }
  __syncthreads();
  for (int it = 0; it < 16; ++it) {
    int lin = it * 256 + threadIdx.x;
    int dl = lin >> 6, sl = lin & 63;
    Vt[((size_t)bh * HD_ + d0 + dl) * S_ + s0 + sl] = t[sl * 66 + dl];
  }
}

// ---------------- fused causal flash attention (v3) ----------------
// v2 -> v3: __launch_bounds__(256,2). v2's (256,3) capped the register budget
// at ~168 and the allocator spilled the kreg/vreg prefetch (live across the
// barrier) to scratch: WRITE_SIZE was 508 MB vs 16 MB ideal — the kernel was
// spill-BW-bound. (256,2) gives a 256-reg budget; ~140 live regs fit with no
// scratch. launch_bounds is a floor, not a cap: if allocation lands <=168,
// HW still co-schedules 3 blocks/CU (LDS 44 KB allows it).
// V prefetch issued after softmax to shorten its live range.
#define KS_LD 136   // 64x128 K tile, padded (stride%128B==16B -> 2-way aliasing, free)
#define VS_LD 72    // 128x64 V^T tile, padded
#define PS_LD 72    // 16x64 P tile per wave, padded
__global__ __launch_bounds__(256, 2)
void attn_fused(const unsigned short* __restrict__ Qb,
                const unsigned short* __restrict__ Kb,
                const unsigned short* __restrict__ Vt,
                unsigned short* __restrict__ Ob) {
  __shared__ __align__(16) unsigned short Ks[64 * KS_LD];
  __shared__ __align__(16) unsigned short Vts[128 * VS_LD];
  __shared__ __align__(16) unsigned short Ps[4 * 16 * PS_LD];

  const int tid = threadIdx.x, lane = tid & 63, w = tid >> 6;
  const int bh = blockIdx.x;                    // fast dim: spreads heads across XCDs
  const int qt = (gridDim.y - 1) - blockIdx.y;  // descending: longest blocks first (LPT)
  const int q0 = qt * 64;
  const int b = bh >> 4, h = bh & 15;
  const int rowq = lane & 15;
  const int koff = (lane >> 4) * 8;
  const int lr0 = (lane >> 4) * 4;
  const size_t qkbase = (size_t)bh * (S_ * HD_);
  const size_t vbase  = (size_t)bh * (HD_ * S_);

  // Q fragments direct from global, held in regs across the whole k-loop
  bf16x8 qf[4];
  {
    const unsigned short* qrow = Qb + qkbase + (size_t)(q0 + w * 16 + rowq) * HD_;
    for (int t = 0; t < 4; ++t) qf[t] = *(const bf16x8*)(qrow + t * 32 + koff);
  }

  // staging decomposition (256 threads, 16B chunks, 4 passes each)
  const int krow = tid >> 4, kcol = (tid & 15) * 8;  // K: 16 rows/pass
  const int vrow = tid >> 3, vcol = (tid & 7) * 8;   // V^T: 32 rows/pass

  f32x4 oacc[8];
  for (int i = 0; i < 8; ++i)
    for (int r = 0; r < 4; ++r) oacc[i][r] = 0.f;
  float m_r[4] = {-3e38f, -3e38f, -3e38f, -3e38f};
  float l_r[4] = {0.f, 0.f, 0.f, 0.f};

  const int nkt = qt + 1;

  // prefetch tile 0 into regs
  float4 kreg[4], vreg[4];
  for (int p = 0; p < 4; ++p) {
    kreg[p] = *(const float4*)(Kb + qkbase + (size_t)(krow + p * 16) * HD_ + kcol);
    vreg[p] = *(const float4*)(Vt + vbase + (size_t)(vrow + p * 32) * S_ + vcol);
  }

  for (int kt = 0; kt < nkt; ++kt) {
    __syncthreads();  // previous tile's readers done
    for (int p = 0; p < 4; ++p)
      *(float4*)&Ks[(krow + p * 16) * KS_LD + kcol] = kreg[p];
    for (int p = 0; p < 4; ++p)
      *(float4*)&Vts[(vrow + p * 32) * VS_LD + vcol] = vreg[p];
    // K prefetch for kt+1: issue early, hide under this tile's compute
    if (kt + 1 < nkt) {
      for (int p = 0; p < 4; ++p)
        kreg[p] = *(const float4*)(Kb + qkbase + (size_t)((kt + 1) * 64 + krow + p * 16) * HD_ + kcol);
    }
    __syncthreads();

    // S = Q K^T : wave handles q-rows [w*16, w*16+16), all 64 keys
    f32x4 sacc[4];
    for (int n = 0; n < 4; ++n)
      for (int r = 0; r < 4; ++r) sacc[n][r] = 0.f;
    for (int t = 0; t < 4; ++t)
      for (int n = 0; n < 4; ++n) {
        bf16x8 bk = *(const bf16x8*)&Ks[(n * 16 + rowq) * KS_LD + t * 32 + koff];
        sacc[n] = __builtin_amdgcn_mfma_f32_16x16x32_bf16(qf[t], bk, sacc[n], 0, 0, 0);
      }

    // scale (+ causal mask on diagonal tile only) + online softmax, in place
    const float scale = 0.08838834764831845f;  // 1/sqrt(128)
    float tmax[4] = {-3e38f, -3e38f, -3e38f, -3e38f};
    if (kt == qt) {
      for (int n = 0; n < 4; ++n) {
        int col = n * 16 + rowq;
        for (int r = 0; r < 4; ++r) {
          int row = w * 16 + lr0 + r;
          float x = sacc[n][r] * scale;
          x = (col <= row) ? x : -1e30f;
          sacc[n][r] = x;
          tmax[r] = fmaxf(tmax[r], x);
        }
      }
    } else {
      for (int n = 0; n < 4; ++n)
        for (int r = 0; r < 4; ++r) {
          float x = sacc[n][r] * scale;
          sacc[n][r] = x;
          tmax[r] = fmaxf(tmax[r], x);
        }
    }
    for (int off = 1; off < 16; off <<= 1)
      for (int r = 0; r < 4; ++r) tmax[r] = fmaxf(tmax[r], __shfl_xor(tmax[r], off));
    float alpha[4];
    for (int r = 0; r < 4; ++r) {
      float mn = fmaxf(m_r[r], tmax[r]);
      alpha[r] = __expf(m_r[r] - mn);
      m_r[r] = mn;
    }
    float rs[4] = {0.f, 0.f, 0.f, 0.f};
    for (int n = 0; n < 4; ++n)
      for (int r = 0; r < 4; ++r) {
        float p = __expf(sacc[n][r] - m_r[r]);
        sacc[n][r] = p;
        rs[r] += p;
      }
    for (int off = 1; off < 16; off <<= 1)
      for (int r = 0; r < 4; ++r) rs[r] += __shfl_xor(rs[r], off);
    for (int r = 0; r < 4; ++r) l_r[r] = l_r[r] * alpha[r] + rs[r];
    for (int nd = 0; nd < 8; ++nd)
      for (int r = 0; r < 4; ++r) oacc[nd][r] *= alpha[r];

    // V prefetch for kt+1: issued here (late) to shorten vreg live range;
    // consumed only at next iter's ds_write, ~400+ cycles away.
    if (kt + 1 < nkt) {
      for (int p = 0; p < 4; ++p)
        vreg[p] = *(const float4*)(Vt + vbase + (size_t)(vrow + p * 32) * S_ + (kt + 1) * 64 + vcol);
    }

    // P: C-layout -> LDS -> A-layout (wave-private region)
    unsigned short* pw = &Ps[w * 16 * PS_LD];
    for (int n = 0; n < 4; ++n)
      for (int r = 0; r < 4; ++r)
        pw[(lr0 + r) * PS_LD + n * 16 + rowq] = f2bf(sacc[n][r]);

    // O += P V
    for (int t2 = 0; t2 < 2; ++t2) {
      bf16x8 pa = *(const bf16x8*)&pw[rowq * PS_LD + t2 * 32 + koff];
      for (int nd = 0; nd < 8; ++nd) {
        bf16x8 vb = *(const bf16x8*)&Vts[(nd * 16 + rowq) * VS_LD + t2 * 32 + koff];
        oacc[nd] = __builtin_amdgcn_mfma_f32_16x16x32_bf16(pa, vb, oacc[nd], 0, 0, 0);
      }
    }
  }

  // epilogue: multiply by 1/l, store bf16 to (B,S,HID)
  float linv[4];
  for (int r = 0; r < 4; ++r) linv[r] = __builtin_amdgcn_rcpf(l_r[r]);
  for (int nd = 0; nd < 8; ++nd) {
    int col = h * HD_ + nd * 16 + rowq;
    for (int r = 0; r < 4; ++r) {
      int row = q0 + w * 16 + lr0 + r;
      Ob[(size_t)(b * S_ + row) * HID_ + col] = f2bf(oacc[nd][r] * linv[r]);
    }
  }
}

// ---------------- launcher ----------------
extern "C" void kernel_launch(void* const* d_in, const int* in_sizes, int n_in,
                              void* d_out, int out_size, void* d_ws, size_t ws_size,
                              hipStream_t stream) {
  (void)in_sizes; (void)n_in; (void)out_size; (void)ws_size;
  const float* hidden = (const float*)d_in[0];
  // d_in[1] = attention_mask (causal; reproduced analytically)
  const int* pos = (const int*)d_in[2];
  const float* Wq = (const float*)d_in[3];
  const float* Wk = (const float*)d_in[4];
  const float* Wv = (const float*)d_in[5];
  const float* Wo = (const float*)d_in[6];
  float* out = (float*)d_out;

  char* ws = (char*)d_ws;
  unsigned short* Xb   = (unsigned short*)(ws);               // 16 MB  (B,S,HID) bf16
  unsigned short* Wqb  = (unsigned short*)(ws + 16777216);    // 8 MB
  unsigned short* Wkb  = (unsigned short*)(ws + 25165824);    // 8 MB
  unsigned short* Wvb  = (unsigned short*)(ws + 33554432);    // 8 MB
  unsigned short* Wob  = (unsigned short*)(ws + 41943040);    // 8 MB
  unsigned short* Qb   = (unsigned short*)(ws + 50331648);    // 16 MB (B,NH,S,HD)
  unsigned short* Kb   = (unsigned short*)(ws + 67108864);    // 16 MB
  unsigned short* Vtmp = (unsigned short*)(ws + 83886080);    // 16 MB (B,S,HID)
  unsigned short* Vtb  = (unsigned short*)(ws + 100663296);   // 16 MB (B,NH,HD,S)
  unsigned short* Ob   = Xb;  // reuse: Xb dead after V GEMM   total ws: 112 MB

  cast_all<<<2048, 256, 0, stream>>>(hidden, Wq, Wk, Wv, Wo, Xb, Wqb, Wkb, Wvb, Wob);

  dim3 gg(HID_ / 128, (B_ * S_) / 128);  // (16, 32)
  gemm_bt<2><<<gg, 256, 0, stream>>>(Xb, Wqb, Qb, B_ * S_, HID_, HID_);
  gemm_bt<2><<<gg, 256, 0, stream>>>(Xb, Wkb, Kb, B_ * S_, HID_, HID_);
  gemm_bt<1><<<gg, 256, 0, stream>>>(Xb, Wvb, Vtmp, B_ * S_, HID_, HID_);

  rope_kernel<<<B_ * NH_ * S_, 64, 0, stream>>>(Qb, Kb, pos);

  dim3 tg(S_ / 64, HD_ / 64, B_ * NH_);  // (32, 2, 32)
  transpose_v<<<tg, 256, 0, stream>>>(Vtmp, Vtb);

  dim3 ag(B_ * NH_, S_ / 64);  // bh fast, qt slow (descending inside kernel)
  attn_fused<<<ag, 256, 0, stream>>>(Qb, Kb, Vtb, Ob);

  gemm_bt<0><<<gg, 256, 0, stream>>>(Ob, Wob, out, B_ * S_, HID_, HID_);
}

// Round 4
// 458.176 us; speedup vs baseline: 1.5078x; 1.1824x over previous
//
#include <hip/hip_runtime.h>

#define B_   2
#define S_   2048
#define HID_ 2048
#define NH_  16
#define HD_  128

typedef float  f32x4  __attribute__((ext_vector_type(4)));
typedef __bf16 bf16x8 __attribute__((ext_vector_type(8)));

__device__ __forceinline__ unsigned short f2bf(float f) {
  union { float fv; unsigned u; } v; v.fv = f;
  unsigned r = v.u + 0x7FFFu + ((v.u >> 16) & 1u);  // RNE
  return (unsigned short)(r >> 16);
}
__device__ __forceinline__ float bf2f(unsigned short h) {
  union { unsigned u; float fv; } v; v.u = ((unsigned)h) << 16;
  return v.fv;
}

// async global->LDS, 16B per lane (GEMM staging only; LDS dst must be contiguous)
__device__ __forceinline__ void gload16(const void* g, void* lds) {
  __builtin_amdgcn_global_load_lds(
      (const __attribute__((address_space(1))) void*)g,
      (__attribute__((address_space(3))) void*)lds, 16, 0, 0);
}

// ---------------- fused cast fp32 -> bf16 for hidden + 4 weights ----------------
#define H4_ (B_ * S_ * HID_ / 4)
#define W4_ (HID_ * HID_ / 4)
__global__ void cast_all(const float* __restrict__ h,  const float* __restrict__ wq,
                         const float* __restrict__ wk, const float* __restrict__ wv,
                         const float* __restrict__ wo,
                         unsigned short* __restrict__ xb,  unsigned short* __restrict__ wqb,
                         unsigned short* __restrict__ wkb, unsigned short* __restrict__ wvb,
                         unsigned short* __restrict__ wob) {
  const int total = H4_ + 4 * W4_;
  int i = blockIdx.x * blockDim.x + threadIdx.x;
  int stride = gridDim.x * blockDim.x;
  for (; i < total; i += stride) {
    const float* src; unsigned short* dst; int j;
    if (i < H4_) { src = h; dst = xb; j = i; }
    else {
      int k = i - H4_, wsel = k >> 20;  // W4_ = 2^20
      j = k & (W4_ - 1);
      src = (wsel == 0) ? wq : (wsel == 1) ? wk : (wsel == 2) ? wv : wo;
      dst = (wsel == 0) ? wqb : (wsel == 1) ? wkb : (wsel == 2) ? wvb : wob;
    }
    float4 v = ((const float4*)src)[j];
    ushort4 o;
    o.x = f2bf(v.x); o.y = f2bf(v.y); o.z = f2bf(v.z); o.w = f2bf(v.w);
    ((ushort4*)dst)[j] = o;
  }
}

// ---------------- GEMM: C[M,N] = A[M,K] * B[N,K]^T (bf16 in, fp32 acc) ----------------
// EPI 0: fp32 row-major; EPI 1: bf16 row-major; EPI 2: bf16 scattered to (B,NH,S,HD)
template <int EPI>
__global__ __launch_bounds__(256, 2)
void gemm_bt(const unsigned short* __restrict__ A,
             const unsigned short* __restrict__ Bw,
             void* __restrict__ Cout, int M, int N, int K) {
  __shared__ __align__(16) unsigned short As[128 * 32];
  __shared__ __align__(16) unsigned short Bs[128 * 32];
  const int tid = threadIdx.x, lane = tid & 63, w = tid >> 6;
  const int n0 = blockIdx.x * 128, m0 = blockIdx.y * 128;
  const int wm = (w & 1) * 64, wn = (w >> 1) * 64;
  const int rowq = lane & 15;
  const int koff = (lane >> 4) * 8;
  const int lr0 = (lane >> 4) * 4;

  f32x4 acc[4][4];
  for (int i = 0; i < 4; ++i)
    for (int j = 0; j < 4; ++j)
      for (int r = 0; r < 4; ++r) acc[i][j][r] = 0.f;

  for (int k0 = 0; k0 < K; k0 += 32) {
    __syncthreads();
    for (int c = 0; c < 2; ++c) {
      int chunk = (w * 2 + c) * 64 + lane;
      int row = chunk >> 2, cc = chunk & 3;
      gload16(A + (size_t)(m0 + row) * K + k0 + cc * 8, As + (w * 2 + c) * 512);
      gload16(Bw + (size_t)(n0 + row) * K + k0 + cc * 8, Bs + (w * 2 + c) * 512);
    }
    __syncthreads();
    bf16x8 af[4], bfv[4];
    for (int i = 0; i < 4; ++i) {
      af[i]  = *(const bf16x8*)&As[(wm + i * 16 + rowq) * 32 + koff];
      bfv[i] = *(const bf16x8*)&Bs[(wn + i * 16 + rowq) * 32 + koff];
    }
    for (int mi = 0; mi < 4; ++mi)
      for (int ni = 0; ni < 4; ++ni)
        acc[mi][ni] = __builtin_amdgcn_mfma_f32_16x16x32_bf16(af[mi], bfv[ni], acc[mi][ni], 0, 0, 0);
  }

  for (int mi = 0; mi < 4; ++mi)
    for (int ni = 0; ni < 4; ++ni)
      for (int r = 0; r < 4; ++r) {
        int r_ = m0 + wm + mi * 16 + lr0 + r;
        int c_ = n0 + wn + ni * 16 + rowq;
        float v = acc[mi][ni][r];
        if (EPI == 0) {
          ((float*)Cout)[(size_t)r_ * N + c_] = v;
        } else if (EPI == 1) {
          ((unsigned short*)Cout)[(size_t)r_ * N + c_] = f2bf(v);
        } else {
          int b = r_ >> 11, s = r_ & 2047, h = c_ >> 7, d = c_ & 127;
          ((unsigned short*)Cout)[(((size_t)(b * NH_ + h) * S_ + s) * HD_) + d] = f2bf(v);
        }
      }
}

// ---------------- RoPE in-place on Q,K in (B,NH,S,HD) bf16 ----------------
__global__ void rope_kernel(unsigned short* __restrict__ Qb,
                            unsigned short* __restrict__ Kb,
                            const int* __restrict__ pos_ids) {
  const int bhs = blockIdx.x;       // (b*NH+h)*S + s
  const int d = threadIdx.x;        // 0..63 (pair d, d+64)
  const int s = bhs & (S_ - 1);
  const int b = bhs >> 15;          // NH_*S_ = 32768
  const int p = pos_ids[b * S_ + s];
  const float f = expf(-(float)d * (9.210340371976184f / 64.f));  // 10000^(-d/64)
  float sn, cs;
  sincosf((float)p * f, &sn, &cs);
  size_t base = (size_t)bhs * HD_;
  {
    float x1 = bf2f(Qb[base + d]), x2 = bf2f(Qb[base + d + 64]);
    Qb[base + d]      = f2bf(x1 * cs - x2 * sn);
    Qb[base + d + 64] = f2bf(x2 * cs + x1 * sn);
  }
  {
    float x1 = bf2f(Kb[base + d]), x2 = bf2f(Kb[base + d + 64]);
    Kb[base + d]      = f2bf(x1 * cs - x2 * sn);
    Kb[base + d + 64] = f2bf(x2 * cs + x1 * sn);
  }
}

// ---------------- transpose V: (B,S,HID) bf16 -> (B,NH,HD,S) bf16 ----------------
__global__ __launch_bounds__(256)
void transpose_v(const unsigned short* __restrict__ Vin,
                 unsigned short* __restrict__ Vt) {
  __shared__ unsigned short t[64 * 66];
  const int s0 = blockIdx.x * 64, d0 = blockIdx.y * 64, bh = blockIdx.z;
  const int b = bh >> 4, h = bh & 15;
  for (int it = 0; it < 16; ++it) {
    int lin = it * 256 + threadIdx.x;
    int sl = lin >> 6, dl = lin & 63;
    t[sl * 66 + dl] = Vin[(size_t)(b * S_ + s0 + sl) * HID_ + h * HD_ + d0 + dl];
  }
  __syncthreads();
  for (int it = 0; it < 16; ++it) {
    int lin = it * 256 + threadIdx.x;
    int dl = lin >> 6, sl = lin & 63;
    Vt[((size_t)bh * HD_ + d0 + dl) * S_ + s0 + sl] = t[sl * 66 + dl];
  }
}

// ---------------- fused causal flash attention (v4) ----------------
// v3 -> v4: SCALARIZED prefetch buffers. v2/v3's float4 kreg[4]/vreg[4]
// allocas were never promoted to VGPRs (VGPR_Count=76, too low to contain
// them) — every iteration stored+reloaded 128 B/thread of scratch:
// 16896 block-iters * 256 thr * 128 B = 553 MB, matching the measured
// WRITE_SIZE of 508-525 MB vs 16 MB ideal. launch_bounds had no effect
// (r3), so it's failed promotion, not budget spill. Named scalars k0..k3 /
// v0..v3 cannot be alloca'd — forced into registers.
#define KS_LD 136   // 64x128 K tile, padded (stride%128B==16B -> 2-way aliasing, free)
#define VS_LD 72    // 128x64 V^T tile, padded
#define PS_LD 72    // 16x64 P tile per wave, padded
__global__ __launch_bounds__(256, 2)
void attn_fused(const unsigned short* __restrict__ Qb,
                const unsigned short* __restrict__ Kb,
                const unsigned short* __restrict__ Vt,
                unsigned short* __restrict__ Ob) {
  __shared__ __align__(16) unsigned short Ks[64 * KS_LD];
  __shared__ __align__(16) unsigned short Vts[128 * VS_LD];
  __shared__ __align__(16) unsigned short Ps[4 * 16 * PS_LD];

  const int tid = threadIdx.x, lane = tid & 63, w = tid >> 6;
  const int bh = blockIdx.x;                    // fast dim: spreads heads across XCDs
  const int qt = (gridDim.y - 1) - blockIdx.y;  // descending: longest blocks first (LPT)
  const int q0 = qt * 64;
  const int b = bh >> 4, h = bh & 15;
  const int rowq = lane & 15;
  const int koff = (lane >> 4) * 8;
  const int lr0 = (lane >> 4) * 4;
  const size_t qkbase = (size_t)bh * (S_ * HD_);
  const size_t vbase  = (size_t)bh * (HD_ * S_);

  // Q fragments direct from global, held in regs across the whole k-loop
  bf16x8 qf0, qf1, qf2, qf3;
  {
    const unsigned short* qrow = Qb + qkbase + (size_t)(q0 + w * 16 + rowq) * HD_;
    qf0 = *(const bf16x8*)(qrow + 0 * 32 + koff);
    qf1 = *(const bf16x8*)(qrow + 1 * 32 + koff);
    qf2 = *(const bf16x8*)(qrow + 2 * 32 + koff);
    qf3 = *(const bf16x8*)(qrow + 3 * 32 + koff);
  }

  // staging decomposition (256 threads, 16B chunks, 4 passes each)
  const int krow = tid >> 4, kcol = (tid & 15) * 8;  // K: 16 rows/pass
  const int vrow = tid >> 3, vcol = (tid & 7) * 8;   // V^T: 32 rows/pass
  const unsigned short* kptr = Kb + qkbase + (size_t)krow * HD_ + kcol;
  const unsigned short* vptr = Vt + vbase + (size_t)vrow * S_ + vcol;

  f32x4 oacc[8];
  for (int i = 0; i < 8; ++i)
    for (int r = 0; r < 4; ++r) oacc[i][r] = 0.f;
  float m_r[4] = {-3e38f, -3e38f, -3e38f, -3e38f};
  float l_r[4] = {0.f, 0.f, 0.f, 0.f};

  const int nkt = qt + 1;

  // prefetch tile 0 into named registers (NOT arrays: arrays were alloca'd
  // to scratch by the compiler, generating 550 MB of spill traffic)
  float4 k0, k1, k2, k3, v0, v1, v2, v3;
  k0 = *(const float4*)(kptr + 0 * 16 * HD_);
  k1 = *(const float4*)(kptr + 1 * 16 * HD_);
  k2 = *(const float4*)(kptr + 2 * 16 * HD_);
  k3 = *(const float4*)(kptr + 3 * 16 * HD_);
  v0 = *(const float4*)(vptr + 0 * 32 * S_);
  v1 = *(const float4*)(vptr + 1 * 32 * S_);
  v2 = *(const float4*)(vptr + 2 * 32 * S_);
  v3 = *(const float4*)(vptr + 3 * 32 * S_);

  for (int kt = 0; kt < nkt; ++kt) {
    __syncthreads();  // previous tile's readers done
    *(float4*)&Ks[(krow + 0 * 16) * KS_LD + kcol] = k0;
    *(float4*)&Ks[(krow + 1 * 16) * KS_LD + kcol] = k1;
    *(float4*)&Ks[(krow + 2 * 16) * KS_LD + kcol] = k2;
    *(float4*)&Ks[(krow + 3 * 16) * KS_LD + kcol] = k3;
    *(float4*)&Vts[(vrow + 0 * 32) * VS_LD + vcol] = v0;
    *(float4*)&Vts[(vrow + 1 * 32) * VS_LD + vcol] = v1;
    *(float4*)&Vts[(vrow + 2 * 32) * VS_LD + vcol] = v2;
    *(float4*)&Vts[(vrow + 3 * 32) * VS_LD + vcol] = v3;
    // K prefetch for kt+1: issue early, hide under this tile's compute
    if (kt + 1 < nkt) {
      const unsigned short* kp = kptr + (size_t)(kt + 1) * 64 * HD_;
      k0 = *(const float4*)(kp + 0 * 16 * HD_);
      k1 = *(const float4*)(kp + 1 * 16 * HD_);
      k2 = *(const float4*)(kp + 2 * 16 * HD_);
      k3 = *(const float4*)(kp + 3 * 16 * HD_);
    }
    __syncthreads();

    // S = Q K^T : wave handles q-rows [w*16, w*16+16), all 64 keys
    f32x4 sacc[4];
    for (int n = 0; n < 4; ++n)
      for (int r = 0; r < 4; ++r) sacc[n][r] = 0.f;
#pragma unroll
    for (int n = 0; n < 4; ++n) {
      const unsigned short* krow_p = &Ks[(n * 16 + rowq) * KS_LD + koff];
      sacc[n] = __builtin_amdgcn_mfma_f32_16x16x32_bf16(qf0, *(const bf16x8*)(krow_p + 0 * 32), sacc[n], 0, 0, 0);
      sacc[n] = __builtin_amdgcn_mfma_f32_16x16x32_bf16(qf1, *(const bf16x8*)(krow_p + 1 * 32), sacc[n], 0, 0, 0);
      sacc[n] = __builtin_amdgcn_mfma_f32_16x16x32_bf16(qf2, *(const bf16x8*)(krow_p + 2 * 32), sacc[n], 0, 0, 0);
      sacc[n] = __builtin_amdgcn_mfma_f32_16x16x32_bf16(qf3, *(const bf16x8*)(krow_p + 3 * 32), sacc[n], 0, 0, 0);
    }

    // scale (+ causal mask on diagonal tile only) + online softmax, in place
    const float scale = 0.08838834764831845f;  // 1/sqrt(128)
    float tmax[4] = {-3e38f, -3e38f, -3e38f, -3e38f};
    if (kt == qt) {
      for (int n = 0; n < 4; ++n) {
        int col = n * 16 + rowq;
        for (int r = 0; r < 4; ++r) {
          int row = w * 16 + lr0 + r;
          float x = sacc[n][r] * scale;
          x = (col <= row) ? x : -1e30f;
          sacc[n][r] = x;
          tmax[r] = fmaxf(tmax[r], x);
        }
      }
    } else {
      for (int n = 0; n < 4; ++n)
        for (int r = 0; r < 4; ++r) {
          float x = sacc[n][r] * scale;
          sacc[n][r] = x;
          tmax[r] = fmaxf(tmax[r], x);
        }
    }
    for (int off = 1; off < 16; off <<= 1)
      for (int r = 0; r < 4; ++r) tmax[r] = fmaxf(tmax[r], __shfl_xor(tmax[r], off));
    float alpha[4];
    for (int r = 0; r < 4; ++r) {
      float mn = fmaxf(m_r[r], tmax[r]);
      alpha[r] = __expf(m_r[r] - mn);
      m_r[r] = mn;
    }
    float rs[4] = {0.f, 0.f, 0.f, 0.f};
    for (int n = 0; n < 4; ++n)
      for (int r = 0; r < 4; ++r) {
        float p = __expf(sacc[n][r] - m_r[r]);
        sacc[n][r] = p;
        rs[r] += p;
      }
    for (int off = 1; off < 16; off <<= 1)
      for (int r = 0; r < 4; ++r) rs[r] += __shfl_xor(rs[r], off);
    for (int r = 0; r < 4; ++r) l_r[r] = l_r[r] * alpha[r] + rs[r];
    for (int nd = 0; nd < 8; ++nd)
      for (int r = 0; r < 4; ++r) oacc[nd][r] *= alpha[r];

    // V prefetch for kt+1 (late: consumed only at next iter's ds_write)
    if (kt + 1 < nkt) {
      const unsigned short* vp = vptr + (size_t)(kt + 1) * 64;
      v0 = *(const float4*)(vp + 0 * 32 * S_);
      v1 = *(const float4*)(vp + 1 * 32 * S_);
      v2 = *(const float4*)(vp + 2 * 32 * S_);
      v3 = *(const float4*)(vp + 3 * 32 * S_);
    }

    // P: C-layout -> LDS -> A-layout (wave-private region)
    unsigned short* pw = &Ps[w * 16 * PS_LD];
    for (int n = 0; n < 4; ++n)
      for (int r = 0; r < 4; ++r)
        pw[(lr0 + r) * PS_LD + n * 16 + rowq] = f2bf(sacc[n][r]);

    // O += P V
#pragma unroll
    for (int t2 = 0; t2 < 2; ++t2) {
      bf16x8 pa = *(const bf16x8*)&pw[rowq * PS_LD + t2 * 32 + koff];
      for (int nd = 0; nd < 8; ++nd) {
        bf16x8 vb = *(const bf16x8*)&Vts[(nd * 16 + rowq) * VS_LD + t2 * 32 + koff];
        oacc[nd] = __builtin_amdgcn_mfma_f32_16x16x32_bf16(pa, vb, oacc[nd], 0, 0, 0);
      }
    }
  }

  // epilogue: multiply by 1/l, store bf16 to (B,S,HID)
  float linv[4];
  for (int r = 0; r < 4; ++r) linv[r] = __builtin_amdgcn_rcpf(l_r[r]);
  for (int nd = 0; nd < 8; ++nd) {
    int col = h * HD_ + nd * 16 + rowq;
    for (int r = 0; r < 4; ++r) {
      int row = q0 + w * 16 + lr0 + r;
      Ob[(size_t)(b * S_ + row) * HID_ + col] = f2bf(oacc[nd][r] * linv[r]);
    }
  }
}

// ---------------- launcher ----------------
extern "C" void kernel_launch(void* const* d_in, const int* in_sizes, int n_in,
                              void* d_out, int out_size, void* d_ws, size_t ws_size,
                              hipStream_t stream) {
  (void)in_sizes; (void)n_in; (void)out_size; (void)ws_size;
  const float* hidden = (const float*)d_in[0];
  // d_in[1] = attention_mask (causal; reproduced analytically)
  const int* pos = (const int*)d_in[2];
  const float* Wq = (const float*)d_in[3];
  const float* Wk = (const float*)d_in[4];
  const float* Wv = (const float*)d_in[5];
  const float* Wo = (const float*)d_in[6];
  float* out = (float*)d_out;

  char* ws = (char*)d_ws;
  unsigned short* Xb   = (unsigned short*)(ws);               // 16 MB  (B,S,HID) bf16
  unsigned short* Wqb  = (unsigned short*)(ws + 16777216);    // 8 MB
  unsigned short* Wkb  = (unsigned short*)(ws + 25165824);    // 8 MB
  unsigned short* Wvb  = (unsigned short*)(ws + 33554432);    // 8 MB
  unsigned short* Wob  = (unsigned short*)(ws + 41943040);    // 8 MB
  unsigned short* Qb   = (unsigned short*)(ws + 50331648);    // 16 MB (B,NH,S,HD)
  unsigned short* Kb   = (unsigned short*)(ws + 67108864);    // 16 MB
  unsigned short* Vtmp = (unsigned short*)(ws + 83886080);    // 16 MB (B,S,HID)
  unsigned short* Vtb  = (unsigned short*)(ws + 100663296);   // 16 MB (B,NH,HD,S)
  unsigned short* Ob   = Xb;  // reuse: Xb dead after V GEMM   total ws: 112 MB

  cast_all<<<2048, 256, 0, stream>>>(hidden, Wq, Wk, Wv, Wo, Xb, Wqb, Wkb, Wvb, Wob);

  dim3 gg(HID_ / 128, (B_ * S_) / 128);  // (16, 32)
  gemm_bt<2><<<gg, 256, 0, stream>>>(Xb, Wqb, Qb, B_ * S_, HID_, HID_);
  gemm_bt<2><<<gg, 256, 0, stream>>>(Xb, Wkb, Kb, B_ * S_, HID_, HID_);
  gemm_bt<1><<<gg, 256, 0, stream>>>(Xb, Wvb, Vtmp, B_ * S_, HID_, HID_);

  rope_kernel<<<B_ * NH_ * S_, 64, 0, stream>>>(Qb, Kb, pos);

  dim3 tg(S_ / 64, HD_ / 64, B_ * NH_);  // (32, 2, 32)
  transpose_v<<<tg, 256, 0, stream>>>(Vtmp, Vtb);

  dim3 ag(B_ * NH_, S_ / 64);  // bh fast, qt slow (descending inside kernel)
  attn_fused<<<ag, 256, 0, stream>>>(Qb, Kb, Vtb, Ob);

  gemm_bt<0><<<gg, 256, 0, stream>>>(Ob, Wob, out, B_ * S_, HID_, HID_);
}

// Round 6
// 422.030 us; speedup vs baseline: 1.6370x; 1.0856x over previous
//
#include <hip/hip_runtime.h>

#define B_   2
#define S_   2048
#define HID_ 2048
#define NH_  16
#define HD_  128
#define MAXTOK_ 2048

typedef float  f32x4  __attribute__((ext_vector_type(4)));
typedef __bf16 bf16x8 __attribute__((ext_vector_type(8)));

__device__ __forceinline__ unsigned short f2bf(float f) {
  union { float fv; unsigned u; } v; v.fv = f;
  unsigned r = v.u + 0x7FFFu + ((v.u >> 16) & 1u);  // RNE
  return (unsigned short)(r >> 16);
}
__device__ __forceinline__ float bf2f(unsigned short h) {
  union { unsigned u; float fv; } v; v.u = ((unsigned)h) << 16;
  return v.fv;
}

// async global->LDS, 16B per lane (GEMM staging only; LDS dst must be contiguous)
__device__ __forceinline__ void gload16(const void* g, void* lds) {
  __builtin_amdgcn_global_load_lds(
      (const __attribute__((address_space(1))) void*)g,
      (__attribute__((address_space(3))) void*)lds, 16, 0, 0);
}

// ---------------- fused cast fp32 -> bf16 for hidden + 4 weights ----------------
// Wq/Wk/Wv destinations are CONTIGUOUS in ws, forming a (3*HID, HID) QKV weight.
#define H4_ (B_ * S_ * HID_ / 4)
#define W4_ (HID_ * HID_ / 4)
__global__ void cast_all(const float* __restrict__ h,  const float* __restrict__ wq,
                         const float* __restrict__ wk, const float* __restrict__ wv,
                         const float* __restrict__ wo,
                         unsigned short* __restrict__ xb,  unsigned short* __restrict__ wqb,
                         unsigned short* __restrict__ wkb, unsigned short* __restrict__ wvb,
                         unsigned short* __restrict__ wob) {
  const int total = H4_ + 4 * W4_;
  int i = blockIdx.x * blockDim.x + threadIdx.x;
  int stride = gridDim.x * blockDim.x;
  for (; i < total; i += stride) {
    const float* src; unsigned short* dst; int j;
    if (i < H4_) { src = h; dst = xb; j = i; }
    else {
      int k = i - H4_, wsel = k >> 20;  // W4_ = 2^20
      j = k & (W4_ - 1);
      src = (wsel == 0) ? wq : (wsel == 1) ? wk : (wsel == 2) ? wv : wo;
      dst = (wsel == 0) ? wqb : (wsel == 1) ? wkb : (wsel == 2) ? wvb : wob;
    }
    float4 v = ((const float4*)src)[j];
    ushort4 o;
    o.x = f2bf(v.x); o.y = f2bf(v.y); o.z = f2bf(v.z); o.w = f2bf(v.w);
    ((ushort4*)dst)[j] = o;
  }
}

// ---------------- GEMM kernels: C[M,N] = A[M,K] * B[N,K]^T, 128x128 tile, BK=32 ----------------

// Fused QKV projection: N = 3*HID = 6144. Epilogue scatters:
//   proj 0 -> Qb (B,NH,S,HD)   proj 1 -> Kb (B,NH,S,HD)   proj 2 -> Vtmp (B,S,HID)
__global__ __launch_bounds__(256, 2)
void gemm_qkv(const unsigned short* __restrict__ A,
              const unsigned short* __restrict__ Bw,
              unsigned short* __restrict__ Qb,
              unsigned short* __restrict__ Kb,
              unsigned short* __restrict__ Vtmp) {
  const int K = HID_;
  __shared__ __align__(16) unsigned short As[128 * 32];
  __shared__ __align__(16) unsigned short Bs[128 * 32];
  const int tid = threadIdx.x, lane = tid & 63, w = tid >> 6;
  const int n0 = blockIdx.x * 128, m0 = blockIdx.y * 128;
  const int wm = (w & 1) * 64, wn = (w >> 1) * 64;
  const int rowq = lane & 15;
  const int koff = (lane >> 4) * 8;
  const int lr0 = (lane >> 4) * 4;

  f32x4 acc[4][4];
  for (int i = 0; i < 4; ++i)
    for (int j = 0; j < 4; ++j)
      for (int r = 0; r < 4; ++r) acc[i][j][r] = 0.f;

  for (int k0 = 0; k0 < K; k0 += 32) {
    __syncthreads();
    for (int c = 0; c < 2; ++c) {
      int chunk = (w * 2 + c) * 64 + lane;
      int row = chunk >> 2, cc = chunk & 3;
      gload16(A + (size_t)(m0 + row) * K + k0 + cc * 8, As + (w * 2 + c) * 512);
      gload16(Bw + (size_t)(n0 + row) * K + k0 + cc * 8, Bs + (w * 2 + c) * 512);
    }
    __syncthreads();
    bf16x8 af[4], bfv[4];
    for (int i = 0; i < 4; ++i) {
      af[i]  = *(const bf16x8*)&As[(wm + i * 16 + rowq) * 32 + koff];
      bfv[i] = *(const bf16x8*)&Bs[(wn + i * 16 + rowq) * 32 + koff];
    }
    for (int mi = 0; mi < 4; ++mi)
      for (int ni = 0; ni < 4; ++ni)
        acc[mi][ni] = __builtin_amdgcn_mfma_f32_16x16x32_bf16(af[mi], bfv[ni], acc[mi][ni], 0, 0, 0);
  }

  for (int mi = 0; mi < 4; ++mi)
    for (int ni = 0; ni < 4; ++ni)
      for (int r = 0; r < 4; ++r) {
        int r_ = m0 + wm + mi * 16 + lr0 + r;
        int c_ = n0 + wn + ni * 16 + rowq;
        float v = acc[mi][ni][r];
        int b = r_ >> 11, s = r_ & 2047;
        int proj = c_ >> 11, cin = c_ & 2047;
        if (proj == 2) {
          Vtmp[(size_t)(b * S_ + s) * HID_ + cin] = f2bf(v);
        } else {
          int hh = cin >> 7, d = cin & 127;
          unsigned short* dst = (proj == 0) ? Qb : Kb;
          dst[(((size_t)(b * NH_ + hh) * S_ + s) * HD_) + d] = f2bf(v);
        }
      }
}

// Output projection: fp32 row-major C.
__global__ __launch_bounds__(256, 2)
void gemm_out(const unsigned short* __restrict__ A,
              const unsigned short* __restrict__ Bw,
              float* __restrict__ Cout) {
  const int N = HID_, K = HID_;
  __shared__ __align__(16) unsigned short As[128 * 32];
  __shared__ __align__(16) unsigned short Bs[128 * 32];
  const int tid = threadIdx.x, lane = tid & 63, w = tid >> 6;
  const int n0 = blockIdx.x * 128, m0 = blockIdx.y * 128;
  const int wm = (w & 1) * 64, wn = (w >> 1) * 64;
  const int rowq = lane & 15;
  const int koff = (lane >> 4) * 8;
  const int lr0 = (lane >> 4) * 4;

  f32x4 acc[4][4];
  for (int i = 0; i < 4; ++i)
    for (int j = 0; j < 4; ++j)
      for (int r = 0; r < 4; ++r) acc[i][j][r] = 0.f;

  for (int k0 = 0; k0 < K; k0 += 32) {
    __syncthreads();
    for (int c = 0; c < 2; ++c) {
      int chunk = (w * 2 + c) * 64 + lane;
      int row = chunk >> 2, cc = chunk & 3;
      gload16(A + (size_t)(m0 + row) * K + k0 + cc * 8, As + (w * 2 + c) * 512);
      gload16(Bw + (size_t)(n0 + row) * K + k0 + cc * 8, Bs + (w * 2 + c) * 512);
    }
    __syncthreads();
    bf16x8 af[4], bfv[4];
    for (int i = 0; i < 4; ++i) {
      af[i]  = *(const bf16x8*)&As[(wm + i * 16 + rowq) * 32 + koff];
      bfv[i] = *(const bf16x8*)&Bs[(wn + i * 16 + rowq) * 32 + koff];
    }
    for (int mi = 0; mi < 4; ++mi)
      for (int ni = 0; ni < 4; ++ni)
        acc[mi][ni] = __builtin_amdgcn_mfma_f32_16x16x32_bf16(af[mi], bfv[ni], acc[mi][ni], 0, 0, 0);
  }

  for (int mi = 0; mi < 4; ++mi)
    for (int ni = 0; ni < 4; ++ni)
      for (int r = 0; r < 4; ++r) {
        int r_ = m0 + wm + mi * 16 + lr0 + r;
        int c_ = n0 + wn + ni * 16 + rowq;
        Cout[(size_t)r_ * N + c_] = acc[mi][ni][r];
      }
}

// ---------------- RoPE: table precompute + coalesced apply ----------------
// Table lives in the (dead after QKV-GEMM) Xb region: (MAXTOK, 64) float2.
__global__ void rope_table(float2* __restrict__ tbl) {
  int i = blockIdx.x * blockDim.x + threadIdx.x;  // p*64 + d
  if (i >= MAXTOK_ * 64) return;
  int p = i >> 6, d = i & 63;
  float f = __expf(-(float)d * (9.210340371976184f / 64.f));  // 10000^(-d/64)
  float sn, cs;
  __sincosf((float)p * f, &sn, &cs);
  tbl[i] = make_float2(cs, sn);
}

// Applies RoPE in place; Q additionally scaled by (1/sqrt(HD))*log2(e) so the
// attention softmax can use exp2 directly on raw QK^T accumulators.
#define QSCALE_ 0.12751744f
__global__ __launch_bounds__(256)
void rope_apply(unsigned short* __restrict__ Qb, unsigned short* __restrict__ Kb,
                const int* __restrict__ pos_ids, const float2* __restrict__ tbl) {
  int i = blockIdx.x * blockDim.x + threadIdx.x;  // bhs*64 + d
  int d = i & 63, bhs = i >> 6;
  int s = bhs & (S_ - 1);
  int b = bhs >> 15;  // NH_*S_ = 32768
  int p = pos_ids[b * S_ + s];
  float2 cssn = tbl[p * 64 + d];
  size_t base = (size_t)bhs * HD_;
  {
    float x1 = bf2f(Qb[base + d]), x2 = bf2f(Qb[base + d + 64]);
    Qb[base + d]      = f2bf((x1 * cssn.x - x2 * cssn.y) * QSCALE_);
    Qb[base + d + 64] = f2bf((x2 * cssn.x + x1 * cssn.y) * QSCALE_);
  }
  {
    float x1 = bf2f(Kb[base + d]), x2 = bf2f(Kb[base + d + 64]);
    Kb[base + d]      = f2bf(x1 * cssn.x - x2 * cssn.y);
    Kb[base + d + 64] = f2bf(x2 * cssn.x + x1 * cssn.y);
  }
}

// ---------------- transpose V: (B,S,HID) bf16 -> (B,NH,HD,S) bf16 ----------------
__global__ __launch_bounds__(256)
void transpose_v(const unsigned short* __restrict__ Vin,
                 unsigned short* __restrict__ Vt) {
  __shared__ unsigned short t[64 * 66];
  const int s0 = blockIdx.x * 64, d0 = blockIdx.y * 64, bh = blockIdx.z;
  const int b = bh >> 4, h = bh & 15;
  for (int it = 0; it < 16; ++it) {
    int lin = it * 256 + threadIdx.x;
    int sl = lin >> 6, dl = lin & 63;
    t[sl * 66 + dl] = Vin[(size_t)(b * S_ + s0 + sl) * HID_ + h * HD_ + d0 + dl];
  }
  __syncthreads();
  for (int it = 0; it < 16; ++it) {
    int lin = it * 256 + threadIdx.x;
    int dl = lin >> 6, sl = lin & 63;
    Vt[((size_t)bh * HD_ + d0 + dl) * S_ + s0 + sl] = t[sl * 66 + dl];
  }
}

// ---------------- fused causal flash attention (v5) ----------------
// v4 -> v5: scores arrive pre-scaled by scale*log2e (folded into Q at RoPE),
// so softmax is p = exp2(x - m), alpha = exp2(dm): drops the per-element scale
// mul and uses native v_exp_f32 without the expf range-reduction prelude.
// Prefetch buffers remain NAMED SCALARS (v4 lesson: arrays -> scratch).
#define KS_LD 136   // 64x128 K tile, padded (16B-aligned rows, 2-way bank aliasing)
#define VS_LD 72    // 128x64 V^T tile, padded
#define PS_LD 72    // 16x64 P tile per wave, padded (b128-aligned; Ps writes ~4-way)
__global__ __launch_bounds__(256, 2)
void attn_fused(const unsigned short* __restrict__ Qb,
                const unsigned short* __restrict__ Kb,
                const unsigned short* __restrict__ Vt,
                unsigned short* __restrict__ Ob) {
  __shared__ __align__(16) unsigned short Ks[64 * KS_LD];
  __shared__ __align__(16) unsigned short Vts[128 * VS_LD];
  __shared__ __align__(16) unsigned short Ps[4 * 16 * PS_LD];

  const int tid = threadIdx.x, lane = tid & 63, w = tid >> 6;
  const int bh = blockIdx.x;                    // fast dim: spreads heads across XCDs
  const int qt = (gridDim.y - 1) - blockIdx.y;  // descending: longest blocks first (LPT)
  const int q0 = qt * 64;
  const int b = bh >> 4, h = bh & 15;
  const int rowq = lane & 15;
  const int koff = (lane >> 4) * 8;
  const int lr0 = (lane >> 4) * 4;
  const size_t qkbase = (size_t)bh * (S_ * HD_);
  const size_t vbase  = (size_t)bh * (HD_ * S_);

  // Q fragments direct from global, held in regs across the whole k-loop
  bf16x8 qf0, qf1, qf2, qf3;
  {
    const unsigned short* qrow = Qb + qkbase + (size_t)(q0 + w * 16 + rowq) * HD_;
    qf0 = *(const bf16x8*)(qrow + 0 * 32 + koff);
    qf1 = *(const bf16x8*)(qrow + 1 * 32 + koff);
    qf2 = *(const bf16x8*)(qrow + 2 * 32 + koff);
    qf3 = *(const bf16x8*)(qrow + 3 * 32 + koff);
  }

  // staging decomposition (256 threads, 16B chunks, 4 passes each)
  const int krow = tid >> 4, kcol = (tid & 15) * 8;  // K: 16 rows/pass
  const int vrow = tid >> 3, vcol = (tid & 7) * 8;   // V^T: 32 rows/pass
  const unsigned short* kptr = Kb + qkbase + (size_t)krow * HD_ + kcol;
  const unsigned short* vptr = Vt + vbase + (size_t)vrow * S_ + vcol;

  f32x4 oacc[8];
  for (int i = 0; i < 8; ++i)
    for (int r = 0; r < 4; ++r) oacc[i][r] = 0.f;
  float m_r[4] = {-3e38f, -3e38f, -3e38f, -3e38f};
  float l_r[4] = {0.f, 0.f, 0.f, 0.f};

  const int nkt = qt + 1;

  // prefetch tile 0 into named registers
  float4 k0, k1, k2, k3, v0, v1, v2, v3;
  k0 = *(const float4*)(kptr + 0 * 16 * HD_);
  k1 = *(const float4*)(kptr + 1 * 16 * HD_);
  k2 = *(const float4*)(kptr + 2 * 16 * HD_);
  k3 = *(const float4*)(kptr + 3 * 16 * HD_);
  v0 = *(const float4*)(vptr + 0 * 32 * S_);
  v1 = *(const float4*)(vptr + 1 * 32 * S_);
  v2 = *(const float4*)(vptr + 2 * 32 * S_);
  v3 = *(const float4*)(vptr + 3 * 32 * S_);

  for (int kt = 0; kt < nkt; ++kt) {
    __syncthreads();  // previous tile's readers done
    *(float4*)&Ks[(krow + 0 * 16) * KS_LD + kcol] = k0;
    *(float4*)&Ks[(krow + 1 * 16) * KS_LD + kcol] = k1;
    *(float4*)&Ks[(krow + 2 * 16) * KS_LD + kcol] = k2;
    *(float4*)&Ks[(krow + 3 * 16) * KS_LD + kcol] = k3;
    *(float4*)&Vts[(vrow + 0 * 32) * VS_LD + vcol] = v0;
    *(float4*)&Vts[(vrow + 1 * 32) * VS_LD + vcol] = v1;
    *(float4*)&Vts[(vrow + 2 * 32) * VS_LD + vcol] = v2;
    *(float4*)&Vts[(vrow + 3 * 32) * VS_LD + vcol] = v3;
    // K prefetch for kt+1: issue early, hide under this tile's compute
    if (kt + 1 < nkt) {
      const unsigned short* kp = kptr + (size_t)(kt + 1) * 64 * HD_;
      k0 = *(const float4*)(kp + 0 * 16 * HD_);
      k1 = *(const float4*)(kp + 1 * 16 * HD_);
      k2 = *(const float4*)(kp + 2 * 16 * HD_);
      k3 = *(const float4*)(kp + 3 * 16 * HD_);
    }
    __syncthreads();

    // S = Q K^T (pre-scaled by scale*log2e via Q)
    f32x4 sacc[4];
    for (int n = 0; n < 4; ++n)
      for (int r = 0; r < 4; ++r) sacc[n][r] = 0.f;
#pragma unroll
    for (int n = 0; n < 4; ++n) {
      const unsigned short* krow_p = &Ks[(n * 16 + rowq) * KS_LD + koff];
      sacc[n] = __builtin_amdgcn_mfma_f32_16x16x32_bf16(qf0, *(const bf16x8*)(krow_p + 0 * 32), sacc[n], 0, 0, 0);
      sacc[n] = __builtin_amdgcn_mfma_f32_16x16x32_bf16(qf1, *(const bf16x8*)(krow_p + 1 * 32), sacc[n], 0, 0, 0);
      sacc[n] = __builtin_amdgcn_mfma_f32_16x16x32_bf16(qf2, *(const bf16x8*)(krow_p + 2 * 32), sacc[n], 0, 0, 0);
      sacc[n] = __builtin_amdgcn_mfma_f32_16x16x32_bf16(qf3, *(const bf16x8*)(krow_p + 3 * 32), sacc[n], 0, 0, 0);
    }

    // causal mask (diagonal tile only) + online softmax in exp2 domain
    float tmax[4] = {-3e38f, -3e38f, -3e38f, -3e38f};
    if (kt == qt) {
      for (int n = 0; n < 4; ++n) {
        int col = n * 16 + rowq;
        for (int r = 0; r < 4; ++r) {
          int row = w * 16 + lr0 + r;
          float x = (col <= row) ? sacc[n][r] : -1e30f;
          sacc[n][r] = x;
          tmax[r] = fmaxf(tmax[r], x);
        }
      }
    } else {
      for (int n = 0; n < 4; ++n)
        for (int r = 0; r < 4; ++r)
          tmax[r] = fmaxf(tmax[r], sacc[n][r]);
    }
    for (int off = 1; off < 16; off <<= 1)
      for (int r = 0; r < 4; ++r) tmax[r] = fmaxf(tmax[r], __shfl_xor(tmax[r], off));
    float alpha[4];
    for (int r = 0; r < 4; ++r) {
      float mn = fmaxf(m_r[r], tmax[r]);
      alpha[r] = __builtin_amdgcn_exp2f(m_r[r] - mn);
      m_r[r] = mn;
    }
    float rs[4] = {0.f, 0.f, 0.f, 0.f};
    for (int n = 0; n < 4; ++n)
      for (int r = 0; r < 4; ++r) {
        float p = __builtin_amdgcn_exp2f(sacc[n][r] - m_r[r]);
        sacc[n][r] = p;
        rs[r] += p;
      }
    for (int off = 1; off < 16; off <<= 1)
      for (int r = 0; r < 4; ++r) rs[r] += __shfl_xor(rs[r], off);
    for (int r = 0; r < 4; ++r) l_r[r] = l_r[r] * alpha[r] + rs[r];
    for (int nd = 0; nd < 8; ++nd)
      for (int r = 0; r < 4; ++r) oacc[nd][r] *= alpha[r];

    // V prefetch for kt+1 (late: consumed only at next iter's ds_write)
    if (kt + 1 < nkt) {
      const unsigned short* vp = vptr + (size_t)(kt + 1) * 64;
      v0 = *(const float4*)(vp + 0 * 32 * S_);
      v1 = *(const float4*)(vp + 1 * 32 * S_);
      v2 = *(const float4*)(vp + 2 * 32 * S_);
      v3 = *(const float4*)(vp + 3 * 32 * S_);
    }

    // P: C-layout -> LDS -> A-layout (wave-private region)
    unsigned short* pw = &Ps[w * 16 * PS_LD];
    for (int n = 0; n < 4; ++n)
      for (int r = 0; r < 4; ++r)
        pw[(lr0 + r) * PS_LD + n * 16 + rowq] = f2bf(sacc[n][r]);

    // O += P V
#pragma unroll
    for (int t2 = 0; t2 < 2; ++t2) {
      bf16x8 pa = *(const bf16x8*)&pw[rowq * PS_LD + t2 * 32 + koff];
      for (int nd = 0; nd < 8; ++nd) {
        bf16x8 vb = *(const bf16x8*)&Vts[(nd * 16 + rowq) * VS_LD + t2 * 32 + koff];
        oacc[nd] = __builtin_amdgcn_mfma_f32_16x16x32_bf16(pa, vb, oacc[nd], 0, 0, 0);
      }
    }
  }

  // epilogue: multiply by 1/l, store bf16 to (B,S,HID)
  float linv[4];
  for (int r = 0; r < 4; ++r) linv[r] = __builtin_amdgcn_rcpf(l_r[r]);
  for (int nd = 0; nd < 8; ++nd) {
    int col = h * HD_ + nd * 16 + rowq;
    for (int r = 0; r < 4; ++r) {
      int row = q0 + w * 16 + lr0 + r;
      Ob[(size_t)(b * S_ + row) * HID_ + col] = f2bf(oacc[nd][r] * linv[r]);
    }
  }
}

// ---------------- launcher ----------------
extern "C" void kernel_launch(void* const* d_in, const int* in_sizes, int n_in,
                              void* d_out, int out_size, void* d_ws, size_t ws_size,
                              hipStream_t stream) {
  (void)in_sizes; (void)n_in; (void)out_size; (void)ws_size;
  const float* hidden = (const float*)d_in[0];
  // d_in[1] = attention_mask (causal; reproduced analytically)
  const int* pos = (const int*)d_in[2];
  const float* Wq = (const float*)d_in[3];
  const float* Wk = (const float*)d_in[4];
  const float* Wv = (const float*)d_in[5];
  const float* Wo = (const float*)d_in[6];
  float* out = (float*)d_out;

  char* ws = (char*)d_ws;
  // NOTE: no trailing backslashes in these comments (r5 bug: "// ... \" spliced
  // the following declaration line into the comment -> undeclared identifier).
  unsigned short* Xb   = (unsigned short*)(ws);               // 16 MB  (B,S,HID) bf16
  unsigned short* Wqb  = (unsigned short*)(ws + 16777216);    // 8 MB  Wq -- Wqb/Wkb/Wvb contiguous:
  unsigned short* Wkb  = (unsigned short*)(ws + 25165824);    // 8 MB  Wk -- one (6144,2048) QKV weight
  unsigned short* Wvb  = (unsigned short*)(ws + 33554432);    // 8 MB  Wv
  unsigned short* Wob  = (unsigned short*)(ws + 41943040);    // 8 MB
  unsigned short* Qb   = (unsigned short*)(ws + 50331648);    // 16 MB (B,NH,S,HD)
  unsigned short* Kb   = (unsigned short*)(ws + 67108864);    // 16 MB
  unsigned short* Vtmp = (unsigned short*)(ws + 83886080);    // 16 MB (B,S,HID)
  unsigned short* Vtb  = (unsigned short*)(ws + 100663296);   // 16 MB (B,NH,HD,S)
  unsigned short* Ob   = Xb;          // Xb dead after QKV GEMM
  float2* tbl          = (float2*)ws; // RoPE table also lives in dead Xb region (1 MB)

  cast_all<<<2048, 256, 0, stream>>>(hidden, Wq, Wk, Wv, Wo, Xb, Wqb, Wkb, Wvb, Wob);

  // fused QKV: C (4096 x 6144) = X (4096x2048) * Wqkv^T
  dim3 gq(3 * HID_ / 128, (B_ * S_) / 128);  // (48, 32) = 1536 blocks, 6/CU
  gemm_qkv<<<gq, 256, 0, stream>>>(Xb, Wqb, Qb, Kb, Vtmp);

  rope_table<<<(MAXTOK_ * 64) / 256, 256, 0, stream>>>(tbl);
  rope_apply<<<(B_ * NH_ * S_ * 64) / 256, 256, 0, stream>>>(Qb, Kb, pos, tbl);

  dim3 tg(S_ / 64, HD_ / 64, B_ * NH_);  // (32, 2, 32)
  transpose_v<<<tg, 256, 0, stream>>>(Vtmp, Vtb);

  dim3 ag(B_ * NH_, S_ / 64);  // bh fast, qt slow (descending inside kernel)
  attn_fused<<<ag, 256, 0, stream>>>(Qb, Kb, Vtb, Ob);

  dim3 go(HID_ / 128, (B_ * S_) / 128);  // (16, 32)
  gemm_out<<<go, 256, 0, stream>>>(Ob, Wob, out);
}